// Round 10
// baseline (764.374 us; speedup 1.0000x reference)
//
#include <hip/hip_runtime.h>
#include <math.h>

#define BDIM 256

// ---------------------------------------------------------------------------
// jax.image.resize (bilinear/triangle, antialias=True) tap weights.
// ---------------------------------------------------------------------------
__device__ __forceinline__ int resize_taps(int out_n, int o, int in_n,
                                           float* w, int* i0) {
  float inv_scale = (float)in_n / (float)out_n;
  float ks = inv_scale > 1.f ? inv_scale : 1.f;
  float sf = ((float)o + 0.5f) * inv_scale - 0.5f;
  int lo = (int)ceilf(sf - ks);
  int hi = (int)floorf(sf + ks);
  if (lo < 0) lo = 0;
  if (hi > in_n - 1) hi = in_n - 1;
  int n = hi - lo + 1;
  float sum = 0.f;
  for (int k = 0; k < n; ++k) {
    float t = 1.f - fabsf((float)(lo + k) - sf) / ks;
    t = t > 0.f ? t : 0.f;
    w[k] = t;
    sum += t;
  }
  float inv = 1.f / sum;
  for (int k = 0; k < n; ++k) w[k] *= inv;
  *i0 = lo;
  return n;
}

__device__ __forceinline__ float resize_one(const float* __restrict__ plane,
                                            int Hi, int Wi, int oy, int ox,
                                            int Ho, int Wo) {
  float wy[8], wx[8];
  int y0, x0;
  int ny = resize_taps(Ho, oy, Hi, wy, &y0);
  int nx = resize_taps(Wo, ox, Wi, wx, &x0);
  float acc = 0.f;
  for (int a = 0; a < ny; ++a) {
    const float* row = plane + (y0 + a) * Wi + x0;
    float r = 0.f;
    for (int b = 0; b < nx; ++b) r += wx[b] * row[b];
    acc += wy[a] * r;
  }
  return acc;
}

// x1s (64ch 64->32) and x2s (64ch 64->128) in one launch.
__global__ void k_resize12(const float* __restrict__ x, float* __restrict__ x1s,
                           float* __restrict__ x2s) {
  int idx = blockIdx.x * BDIM + threadIdx.x;
  if (idx < 64 * 32 * 32) {
    int ox = idx & 31, oy = (idx >> 5) & 31, c = idx >> 10;
    x1s[idx] = resize_one(x + c * 4096, 64, 64, oy, ox, 32, 32);
  } else {
    int j = idx - 65536;
    if (j < 64 * 128 * 128) {
      int ox = j & 127, oy = (j >> 7) & 127, c = j >> 14;
      x2s[j] = resize_one(x + c * 4096, 64, 64, oy, ox, 128, 128);
    }
  }
}

// generic (used for x3s: 64ch 128->256)
__global__ void k_resize(const float* __restrict__ in, float* __restrict__ out,
                         int C, int Hi, int Wi, int Ho, int Wo) {
  int idx = blockIdx.x * BDIM + threadIdx.x;
  if (idx >= C * Ho * Wo) return;
  int ox = idx % Wo;
  int t = idx / Wo;
  int oy = t % Ho;
  int c = t / Ho;
  out[idx] = resize_one(in + (size_t)c * Hi * Wi, Hi, Wi, oy, ox, Ho, Wo);
}

// ---------------------------------------------------------------------------
// Weight transpose: deform w_c[i] (16,64,3,3) -> [k][c][o] (9216 each);
// conv w_off[i] (18,64,3,3) -> [k][c][o] (10368 each) at base 36864.
// ---------------------------------------------------------------------------
__global__ void k_wtrans(const float* __restrict__ d0, const float* __restrict__ d1,
                         const float* __restrict__ d2, const float* __restrict__ d3,
                         const float* __restrict__ c0, const float* __restrict__ c1,
                         const float* __restrict__ c2, const float* __restrict__ c3,
                         float* __restrict__ dst) {
  int idx = blockIdx.x * BDIM + threadIdx.x;
  if (idx < 36864) {
    int i = idx / 9216, r = idx % 9216;
    int o = r % 16, t = r / 16, c = t % 64, k = t / 64;
    const float* s = i == 0 ? d0 : i == 1 ? d1 : i == 2 ? d2 : d3;
    dst[idx] = s[(o * 64 + c) * 9 + k];
  } else if (idx < 36864 + 41472) {
    int j = idx - 36864;
    int i = j / 10368, r = j % 10368;
    int o = r % 18, t = r / 18, c = t % 64, k = t / 64;
    const float* s = i == 0 ? c0 : i == 1 ? c1 : i == 2 ? c2 : c3;
    dst[idx] = s[(o * 64 + c) * 9 + k];
  }
}

// ---------------------------------------------------------------------------
// FUSED offset-conv + deformable conv + leaky, all 4 scales, 2 PIXELS/LANE.
// Block = 512 thr = 8 waves; wave g owns channels [8g,8g+8); lane owns pixels
// p0 = base+lane and p1 = base+lane+64. One scalar weight batch feeds 2x FMAs
// (amortizes s_load latency). LDS reduce runs in two px-rounds.
// ---------------------------------------------------------------------------
struct FArgs {
  const float* in[4];
  const float* wc[4];   // conv weights [k][c][o18]
  const float* bc[4];   // conv bias
  const float* wd[4];   // deform weights [k][c][o16] (crossed)
  const float* bd[4];   // deform bias (crossed)
  float* out[4];        // a1, a0, a2, a3
  int cut0, cut1, cut2;
};

__global__ __launch_bounds__(512, 4) void k_fused(FArgs A) {
  __shared__ float red[8][64][19];   // 38.9 KB
  int b = blockIdx.x;
  int s = (b >= A.cut0) + (b >= A.cut1) + (b >= A.cut2);
  int b0 = (s == 0) ? 0 : (s == 1 ? A.cut0 : (s == 2 ? A.cut1 : A.cut2));
  int H = 32 << s, W = H, lw = 5 + s, HW = H * W;
  int pad = 4 - s, dil = pad;
  const float* in = A.in[s];
  int tid = threadIdx.x, lane = tid & 63;
  int gv = tid >> 6;
  int g = __builtin_amdgcn_readfirstlane(gv);
  int p0 = (b - b0) * 128 + lane, p1 = p0 + 64;
  int py0 = p0 >> lw, px0 = p0 & (W - 1);
  int py1 = p1 >> lw, px1 = p1 & (W - 1);
  const float* ipg = in + (size_t)(g * 8) * HW;

  // ---------------- phase A: offset conv (18 ch), partial over 8 channels
  float accA0[18], accA1[18];
#pragma unroll
  for (int o = 0; o < 18; ++o) { accA0[o] = 0.f; accA1[o] = 0.f; }
  {
    const float* wT = A.wc[s];
#pragma unroll
    for (int ky = 0; ky < 3; ++ky) {
#pragma unroll
      for (int kx = 0; kx < 3; ++kx) {
        int k = ky * 3 + kx;
        int yy0 = py0 + ky - 1, xx0 = px0 + kx - 1;
        float m0 = (yy0 >= 0 && yy0 < H && xx0 >= 0 && xx0 < W) ? 1.f : 0.f;
        int ai0 = min(max(yy0, 0), H - 1) * W + min(max(xx0, 0), W - 1);
        int yy1 = py1 + ky - 1, xx1 = px1 + kx - 1;
        float m1 = (yy1 >= 0 && yy1 < H && xx1 >= 0 && xx1 < W) ? 1.f : 0.f;
        int ai1 = min(max(yy1, 0), H - 1) * W + min(max(xx1, 0), W - 1);
        const float* ip = ipg;
        const float* wk = wT + (size_t)(k * 64 + g * 8) * 18;
#pragma unroll
        for (int c = 0; c < 8; ++c, ip += HW, wk += 18) {
          float v0 = ip[ai0] * m0;
          float v1 = ip[ai1] * m1;
#pragma unroll
          for (int o = 0; o < 18; ++o) {
            accA0[o] += wk[o] * v0;
            accA1[o] += wk[o] * v1;
          }
        }
      }
    }
  }
  // reduce phase A in two px rounds; every thread needs off for its 2 px.
  float off0[18], off1[18];
  {
    const float* bc = A.bc[s];
#pragma unroll
    for (int o = 0; o < 18; ++o) red[gv][lane][o] = accA0[o];
    __syncthreads();
#pragma unroll
    for (int o = 0; o < 18; ++o) {
      float v = bc[o];
#pragma unroll
      for (int r = 0; r < 8; ++r) v += red[r][lane][o];
      off0[o] = v;
    }
    __syncthreads();
#pragma unroll
    for (int o = 0; o < 18; ++o) red[gv][lane][o] = accA1[o];
    __syncthreads();
#pragma unroll
    for (int o = 0; o < 18; ++o) {
      float v = bc[o];
#pragma unroll
      for (int r = 0; r < 8; ++r) v += red[r][lane][o];
      off1[o] = v;
    }
    __syncthreads();
  }

  // ---------------- phase B: deformable conv (16 ch) using off0/off1
  float acc0[16], acc1[16];
#pragma unroll
  for (int o = 0; o < 16; ++o) { acc0[o] = 0.f; acc1[o] = 0.f; }
  {
    const float* wT = A.wd[s];
#pragma unroll
    for (int ky = 0; ky < 3; ++ky) {
#pragma unroll
      for (int kx = 0; kx < 3; ++kx) {
        int k = ky * 3 + kx;
        // px0 tap geometry
        float pyf = (float)(py0 - pad + ky * dil) + off0[2 * k];
        float pxf = (float)(px0 - pad + kx * dil) + off0[2 * k + 1];
        float fy0 = floorf(pyf), fx0 = floorf(pxf);
        float wy = pyf - fy0, wxv = pxf - fx0;
        int y0 = (int)fy0, x0 = (int)fx0;
        float xg = (x0 >= -1 && x0 <= W - 1) ? 1.f : 0.f;
        float r0 = (1.f - wy) * ((y0 >= 0 && y0 < H) ? xg : 0.f);
        float r1 = wy * ((y0 + 1 >= 0 && y0 + 1 < H) ? xg : 0.f);
        float cl = 1.f - wxv, cr = wxv;
        bool xlo = x0 < 0, xhi = x0 > W - 2;
        float U00 = xlo ? r0 * cr : (xhi ? 0.f : r0 * cl);
        float U01 = xlo ? 0.f : (xhi ? r0 * cl : r0 * cr);
        float U10 = xlo ? r1 * cr : (xhi ? 0.f : r1 * cl);
        float U11 = xlo ? 0.f : (xhi ? r1 * cl : r1 * cr);
        int ax = min(max(x0, 0), W - 2);
        int cy0 = min(max(y0, 0), H - 1);
        int cy1 = min(max(y0 + 1, 0), H - 1);
        int A0 = cy0 * W + ax, A1 = cy1 * W + ax;
        // px1 tap geometry
        float pyg = (float)(py1 - pad + ky * dil) + off1[2 * k];
        float pxg = (float)(px1 - pad + kx * dil) + off1[2 * k + 1];
        float fy1 = floorf(pyg), fx1 = floorf(pxg);
        float wy1 = pyg - fy1, wx1 = pxg - fx1;
        int y1 = (int)fy1, x1 = (int)fx1;
        float xg1 = (x1 >= -1 && x1 <= W - 1) ? 1.f : 0.f;
        float s0 = (1.f - wy1) * ((y1 >= 0 && y1 < H) ? xg1 : 0.f);
        float s1 = wy1 * ((y1 + 1 >= 0 && y1 + 1 < H) ? xg1 : 0.f);
        float dl = 1.f - wx1, dr = wx1;
        bool ylo = x1 < 0, yhi = x1 > W - 2;
        float V00 = ylo ? s0 * dr : (yhi ? 0.f : s0 * dl);
        float V01 = ylo ? 0.f : (yhi ? s0 * dl : s0 * dr);
        float V10 = ylo ? s1 * dr : (yhi ? 0.f : s1 * dl);
        float V11 = ylo ? 0.f : (yhi ? s1 * dl : s1 * dr);
        int bx = min(max(x1, 0), W - 2);
        int dy0 = min(max(y1, 0), H - 1);
        int dy1 = min(max(y1 + 1, 0), H - 1);
        int B0 = dy0 * W + bx, B1 = dy1 * W + bx;
        const float* ip = ipg;
        const float* wk = wT + (size_t)(k * 64 + g * 8) * 16;
#pragma unroll
        for (int c = 0; c < 8; ++c, ip += HW, wk += 16) {
          float sv0 = U00 * ip[A0] + U01 * ip[A0 + 1] +
                      U10 * ip[A1] + U11 * ip[A1 + 1];
          float sv1 = V00 * ip[B0] + V01 * ip[B0 + 1] +
                      V10 * ip[B1] + V11 * ip[B1 + 1];
#pragma unroll
          for (int o = 0; o < 16; ++o) {
            acc0[o] += wk[o] * sv0;
            acc1[o] += wk[o] * sv1;
          }
        }
      }
    }
  }
  // reduce + store, two px rounds (wave 0 stores)
  const float* bd = A.bd[s];
  float* out = A.out[s];
  if (gv) {
#pragma unroll
    for (int o = 0; o < 16; ++o) red[gv - 1][lane][o] = acc0[o];
  }
  __syncthreads();
  if (!gv) {
#pragma unroll
    for (int o = 0; o < 16; ++o) {
      float v = acc0[o] + bd[o];
#pragma unroll
      for (int r = 0; r < 7; ++r) v += red[r][lane][o];
      v = v >= 0.f ? v : 0.01f * v;
      out[(size_t)o * HW + p0] = v;
    }
  }
  __syncthreads();
  if (gv) {
#pragma unroll
    for (int o = 0; o < 16; ++o) red[gv - 1][lane][o] = acc1[o];
  }
  __syncthreads();
  if (!gv) {
#pragma unroll
    for (int o = 0; o < 16; ++o) {
      float v = acc1[o] + bd[o];
#pragma unroll
      for (int r = 0; r < 7; ++r) v += red[r][lane][o];
      v = v >= 0.f ? v : 0.01f * v;
      out[(size_t)o * HW + p1] = v;
    }
  }
}

// ---------------------------------------------------------------------------
// Horizontal downsample pass: a3 (16,256,256) -> t3 (16,256,64) 8 taps;
// a2 (16,128,128) -> t2 (16,128,64) 4 taps.
// ---------------------------------------------------------------------------
__global__ void k_hpass(const float* __restrict__ a2, const float* __restrict__ a3,
                        float* __restrict__ t2, float* __restrict__ t3) {
  int idx = blockIdx.x * BDIM + threadIdx.x;
  if (idx < 262144) {
    int ox = idx & 63, y = (idx >> 6) & 255, c = idx >> 14;
    float wx[8];
    int x0;
    int n = resize_taps(64, ox, 256, wx, &x0);
    const float* row = a3 + (size_t)c * 65536 + y * 256 + x0;
    float r = 0.f;
    for (int b = 0; b < n; ++b) r += wx[b] * row[b];
    t3[idx] = r;
  } else {
    int j = idx - 262144;
    if (j < 131072) {
      int ox = j & 63, y = (j >> 6) & 127, c = j >> 13;
      float wx[8];
      int x0;
      int n = resize_taps(64, ox, 128, wx, &x0);
      const float* row = a2 + (size_t)c * 16384 + y * 128 + x0;
      float r = 0.f;
      for (int b = 0; b < n; ++b) r += wx[b] * row[b];
      t2[j] = r;
    }
  }
}

__device__ __forceinline__ float gelu_f(float x) {
  return 0.5f * x * (1.f + erff(x * 0.70710678118654752f));
}

// Vertical taps + gelu combine.
__global__ void k_final2(const float* __restrict__ a0, const float* __restrict__ a1,
                         const float* __restrict__ t2, const float* __restrict__ t3,
                         float* __restrict__ out) {
  int i = blockIdx.x * BDIM + threadIdx.x;  // [0, 65536)
  int x = i & 63, y = (i >> 6) & 63, c = i >> 12;
  float x1r = resize_one(a1 + c * 1024, 32, 32, y, x, 64, 64);
  float wv[8];
  int y0;
  int n2 = resize_taps(64, y, 128, wv, &y0);
  const float* tp2 = t2 + (size_t)c * 8192 + y0 * 64 + x;
  float x2r = 0.f;
  for (int a = 0; a < n2; ++a) x2r += wv[a] * tp2[a * 64];
  int n3 = resize_taps(64, y, 256, wv, &y0);
  const float* tp3 = t3 + (size_t)c * 16384 + y0 * 64 + x;
  float x3r = 0.f;
  for (int a = 0; a < n3; ++a) x3r += wv[a] * tp3[a * 64];
  float av = a0[i];
  float l = gelu_f(x1r);
  float m = gelu_f(av - l);
  float h = gelu_f(x2r - av);
  float sv = gelu_f(x3r - x2r);
  out[i] = l;
  out[65536 + i] = m;
  out[131072 + i] = h;
  out[196608 + i] = sv;
}

static inline int cdiv(int a, int b) { return (a + b - 1) / b; }

extern "C" void kernel_launch(void* const* d_in, const int* in_sizes, int n_in,
                              void* d_out, int out_size, void* d_ws, size_t ws_size,
                              hipStream_t stream) {
  (void)in_sizes; (void)n_in; (void)out_size; (void)ws_size;
  const float* x = (const float*)d_in[0];
  const float* w_off[4] = {(const float*)d_in[1], (const float*)d_in[5],
                           (const float*)d_in[9], (const float*)d_in[13]};
  const float* b_off[4] = {(const float*)d_in[2], (const float*)d_in[6],
                           (const float*)d_in[10], (const float*)d_in[14]};
  const float* w_c[4] = {(const float*)d_in[3], (const float*)d_in[7],
                         (const float*)d_in[11], (const float*)d_in[15]};
  const float* b_c[4] = {(const float*)d_in[4], (const float*)d_in[8],
                         (const float*)d_in[12], (const float*)d_in[16]};
  float* out = (float*)d_out;

  // Workspace (floats), lifetime-aliased; peak 7,166,464 f = 28.7 MB.
  float* ws = (float*)d_ws;
  float* a0 = ws;                  // [0, 65536)
  float* a1 = ws + 65536;          // [65536, 81920)
  float* a2 = ws + 81920;          // [81920, 344064)
  float* wT = ws + 344064;         // [344064, 422400)
  float* x1s = ws + 422400;        // [422400, 487936)   dead after k_fused
  float* t3 = ws + 422400;         // ALIAS x1s+ (written post-fused)
  float* t2 = ws + 684544;         // [684544, 815616)
  float* x2s = ws + 875008;        // [875008, 1923584)
  float* x3s = ws + 1923584;       // [1923584, 6117888)
  float* a3 = ws + 6117888;        // [6117888, 7166464)
  float* wTd = wT;                 // 4 x 9216
  float* wTc = wT + 36864;         // 4 x 10368

  FArgs fa;
  const float* ins[4] = {x1s, x, x2s, x3s};
  float* as[4] = {a1, a0, a2, a3};
  for (int s = 0; s < 4; ++s) {
    fa.in[s] = ins[s];
    fa.wc[s] = wTc + s * 10368;
    fa.bc[s] = b_off[s];
    fa.wd[s] = wTd + (3 - s) * 9216;
    fa.bd[s] = b_c[3 - s];
    fa.out[s] = as[s];
  }
  fa.cut0 = 8; fa.cut1 = 40; fa.cut2 = 168;   // 128 px per block

  k_wtrans<<<cdiv(78336, BDIM), BDIM, 0, stream>>>(
      w_c[0], w_c[1], w_c[2], w_c[3], w_off[0], w_off[1], w_off[2], w_off[3], wT);
  k_resize12<<<cdiv(65536 + 1048576, BDIM), BDIM, 0, stream>>>(x, x1s, x2s);
  k_resize<<<cdiv(64 * 256 * 256, BDIM), BDIM, 0, stream>>>(x2s, x3s, 64, 128, 128, 256, 256);
  k_fused<<<680, 512, 0, stream>>>(fa);
  k_hpass<<<cdiv(262144 + 131072, BDIM), BDIM, 0, stream>>>(a2, a3, t2, t3);
  k_final2<<<cdiv(65536, BDIM), BDIM, 0, stream>>>(a0, a1, t2, t3, out);
}

// Round 11
// 417.567 us; speedup vs baseline: 1.8305x; 1.8305x over previous
//
#include <hip/hip_runtime.h>
#include <math.h>

#define BDIM 256

// ---------------------------------------------------------------------------
// jax.image.resize (bilinear/triangle, antialias=True) tap weights.
// ---------------------------------------------------------------------------
__device__ __forceinline__ int resize_taps(int out_n, int o, int in_n,
                                           float* w, int* i0) {
  float inv_scale = (float)in_n / (float)out_n;
  float ks = inv_scale > 1.f ? inv_scale : 1.f;
  float sf = ((float)o + 0.5f) * inv_scale - 0.5f;
  int lo = (int)ceilf(sf - ks);
  int hi = (int)floorf(sf + ks);
  if (lo < 0) lo = 0;
  if (hi > in_n - 1) hi = in_n - 1;
  int n = hi - lo + 1;
  float sum = 0.f;
  for (int k = 0; k < n; ++k) {
    float t = 1.f - fabsf((float)(lo + k) - sf) / ks;
    t = t > 0.f ? t : 0.f;
    w[k] = t;
    sum += t;
  }
  float inv = 1.f / sum;
  for (int k = 0; k < n; ++k) w[k] *= inv;
  *i0 = lo;
  return n;
}

__device__ __forceinline__ float resize_one(const float* __restrict__ plane,
                                            int Hi, int Wi, int oy, int ox,
                                            int Ho, int Wo) {
  float wy[8], wx[8];
  int y0, x0;
  int ny = resize_taps(Ho, oy, Hi, wy, &y0);
  int nx = resize_taps(Wo, ox, Wi, wx, &x0);
  float acc = 0.f;
  for (int a = 0; a < ny; ++a) {
    const float* row = plane + (y0 + a) * Wi + x0;
    float r = 0.f;
    for (int b = 0; b < nx; ++b) r += wx[b] * row[b];
    acc += wy[a] * r;
  }
  return acc;
}

// ---------------------------------------------------------------------------
// FRONT kernel: everything that depends only on inputs, one launch.
//   [0, 65536)            x1s  (64ch 64->32)
//   [65536, 1114112)      x2s  (64ch 64->128)
//   [1114112, 5308416)    x3s  (64ch 64->256, composed 2x·2x inline)
//   [5308416, 5386752)    weight transpose -> wT  [k][c][o]
// ---------------------------------------------------------------------------
__global__ void k_front(const float* __restrict__ x, float* __restrict__ x1s,
                        float* __restrict__ x2s, float* __restrict__ x3s,
                        const float* __restrict__ d0, const float* __restrict__ d1,
                        const float* __restrict__ d2, const float* __restrict__ d3,
                        const float* __restrict__ c0, const float* __restrict__ c1,
                        const float* __restrict__ c2, const float* __restrict__ c3,
                        float* __restrict__ wT) {
  int idx = blockIdx.x * BDIM + threadIdx.x;
  if (idx < 65536) {
    int ox = idx & 31, oy = (idx >> 5) & 31, c = idx >> 10;
    x1s[idx] = resize_one(x + c * 4096, 64, 64, oy, ox, 32, 32);
  } else if (idx < 1114112) {
    int j = idx - 65536;
    int ox = j & 127, oy = (j >> 7) & 127, c = j >> 14;
    x2s[j] = resize_one(x + c * 4096, 64, 64, oy, ox, 128, 128);
  } else if (idx < 5308416) {
    int j = idx - 1114112;
    int ox = j & 255, oy = (j >> 8) & 255, c = j >> 16;
    // x3s = resize(x2s, 256) with x2s values recomputed inline from x
    float wy2[2], wx2[2];
    int ty0, tx0;
    int ny = resize_taps(256, oy, 128, wy2, &ty0);
    int nx = resize_taps(256, ox, 128, wx2, &tx0);
    const float* xc = x + c * 4096;
    float acc = 0.f;
    for (int a = 0; a < ny; ++a)
      for (int b = 0; b < nx; ++b)
        acc += wy2[a] * wx2[b] *
               resize_one(xc, 64, 64, ty0 + a, tx0 + b, 128, 128);
    x3s[j] = acc;
  } else if (idx < 5386752) {
    int w = idx - 5308416;
    if (w < 36864) {
      int i = w / 9216, r = w % 9216;
      int o = r % 16, t = r / 16, c = t % 64, k = t / 64;
      const float* s = i == 0 ? d0 : i == 1 ? d1 : i == 2 ? d2 : d3;
      wT[w] = s[(o * 64 + c) * 9 + k];
    } else {
      int j = w - 36864;
      int i = j / 10368, r = j % 10368;
      int o = r % 18, t = r / 18, c = t % 64, k = t / 64;
      const float* s = i == 0 ? c0 : i == 1 ? c1 : i == 2 ? c2 : c3;
      wT[w] = s[(o * 64 + c) * 9 + k];
    }
  }
}

// ---------------------------------------------------------------------------
// FUSED offset-conv + deformable conv + leaky, all 4 scales in one grid.
// Block = 512 thr = 8 waves; wave g owns channels [8g,8g+8) for 64 px (lane).
// Phase A: partial conv18 -> LDS reduce -> per-thread off[18] in regs.
// Phase B: deform gathers using off; LDS reduce; wave 0 stores.
// Weights [k][c][o] via wave-uniform scalar loads.
// launch_bounds(512,3): ~170-VGPR budget (measured occupancy was ~2.9
// waves/SIMD anyway; R10's 2px/lane spilled, R9's (512,4) left ILP on table).
// ---------------------------------------------------------------------------
struct FArgs {
  const float* in[4];
  const float* wc[4];   // conv weights [k][c][o18]
  const float* bc[4];   // conv bias
  const float* wd[4];   // deform weights [k][c][o16] (crossed)
  const float* bd[4];   // deform bias (crossed)
  float* out[4];        // a1, a0, a2, a3
  int cut0, cut1, cut2;
};

__global__ __launch_bounds__(512, 3) void k_fused(FArgs A) {
  __shared__ float red[8][64][19];   // 38.9 KB
  int b = blockIdx.x;
  int s = (b >= A.cut0) + (b >= A.cut1) + (b >= A.cut2);
  int b0 = (s == 0) ? 0 : (s == 1 ? A.cut0 : (s == 2 ? A.cut1 : A.cut2));
  int H = 32 << s, W = H, lw = 5 + s, HW = H * W;
  int pad = 4 - s, dil = pad;
  const float* in = A.in[s];
  int tid = threadIdx.x, lane = tid & 63;
  int g = __builtin_amdgcn_readfirstlane(tid >> 6);
  int p = (b - b0) * 64 + lane;
  int py = p >> lw, px = p & (W - 1);
  const float* ipg = in + (size_t)(g * 8) * HW;

  // ---------------- phase A: offset conv (18 ch), partial over 8 channels
  {
    float accA[18];
#pragma unroll
    for (int o = 0; o < 18; ++o) accA[o] = 0.f;
    const float* wT = A.wc[s];
#pragma unroll
    for (int ky = 0; ky < 3; ++ky) {
#pragma unroll
      for (int kx = 0; kx < 3; ++kx) {
        int k = ky * 3 + kx;
        int yy = py + ky - 1, xx = px + kx - 1;
        float msk = (yy >= 0 && yy < H && xx >= 0 && xx < W) ? 1.f : 0.f;
        int ai = min(max(yy, 0), H - 1) * W + min(max(xx, 0), W - 1);
        const float* ip = ipg + ai;
        const float* wk = wT + (size_t)(k * 64 + g * 8) * 18;
#pragma unroll
        for (int c = 0; c < 8; ++c, ip += HW, wk += 18) {
          float v = *ip * msk;
#pragma unroll
          for (int o = 0; o < 18; ++o) accA[o] += wk[o] * v;
        }
      }
    }
    int gv = tid >> 6;
#pragma unroll
    for (int o = 0; o < 18; ++o) red[gv][lane][o] = accA[o];
  }
  __syncthreads();
  float off[18];
  {
    const float* bc = A.bc[s];
#pragma unroll
    for (int o = 0; o < 18; ++o) {
      float v = bc[o];
#pragma unroll
      for (int r = 0; r < 8; ++r) v += red[r][lane][o];
      off[o] = v;
    }
  }
  __syncthreads();   // all reads of red done before phase-B overwrites

  // ---------------- phase B: deformable conv (16 ch) using off
  float acc[16];
#pragma unroll
  for (int o = 0; o < 16; ++o) acc[o] = 0.f;
  {
    const float* wT = A.wd[s];
#pragma unroll
    for (int ky = 0; ky < 3; ++ky) {
#pragma unroll
      for (int kx = 0; kx < 3; ++kx) {
        int k = ky * 3 + kx;
        float dy = off[2 * k];
        float dx = off[2 * k + 1];
        float pyf = (float)(py - pad + ky * dil) + dy;
        float pxf = (float)(px - pad + kx * dil) + dx;
        float fy0 = floorf(pyf), fx0 = floorf(pxf);
        float wy = pyf - fy0, wxv = pxf - fx0;
        int y0 = (int)fy0, x0 = (int)fx0;
        float xg = (x0 >= -1 && x0 <= W - 1) ? 1.f : 0.f;
        float r0 = (1.f - wy) * ((y0 >= 0 && y0 < H) ? xg : 0.f);
        float r1 = wy * ((y0 + 1 >= 0 && y0 + 1 < H) ? xg : 0.f);
        float cl = 1.f - wxv, cr = wxv;
        bool xlo = x0 < 0, xhi = x0 > W - 2;
        float W00 = xlo ? r0 * cr : (xhi ? 0.f : r0 * cl);
        float W01 = xlo ? 0.f : (xhi ? r0 * cl : r0 * cr);
        float W10 = xlo ? r1 * cr : (xhi ? 0.f : r1 * cl);
        float W11 = xlo ? 0.f : (xhi ? r1 * cl : r1 * cr);
        int ax = min(max(x0, 0), W - 2);
        int cy0 = min(max(y0, 0), H - 1);
        int cy1 = min(max(y0 + 1, 0), H - 1);
        int A0 = cy0 * W + ax, A1 = cy1 * W + ax;
        const float* ip = ipg;
        const float* wk = wT + (size_t)(k * 64 + g * 8) * 16;
#pragma unroll
        for (int c = 0; c < 8; ++c, ip += HW, wk += 16) {
          const float* r0p = ip + A0;
          const float* r1p = ip + A1;
          float sv = W00 * r0p[0] + W01 * r0p[1] + W10 * r1p[0] + W11 * r1p[1];
#pragma unroll
          for (int o = 0; o < 16; ++o) acc[o] += wk[o] * sv;
        }
      }
    }
  }
  int gv = tid >> 6;
  if (gv) {
#pragma unroll
    for (int o = 0; o < 16; ++o) red[gv - 1][lane][o] = acc[o];
  }
  __syncthreads();
  if (!gv) {
    const float* bd = A.bd[s];
    float* out = A.out[s];
#pragma unroll
    for (int o = 0; o < 16; ++o) {
      float v = acc[o] + bd[o];
#pragma unroll
      for (int r = 0; r < 7; ++r) v += red[r][lane][o];
      v = v >= 0.f ? v : 0.01f * v;
      out[(size_t)o * HW + p] = v;
    }
  }
}

// ---------------------------------------------------------------------------
// Horizontal downsample pass: a3 (16,256,256) -> t3 (16,256,64) 8 taps;
// a2 (16,128,128) -> t2 (16,128,64) 4 taps.
// ---------------------------------------------------------------------------
__global__ void k_hpass(const float* __restrict__ a2, const float* __restrict__ a3,
                        float* __restrict__ t2, float* __restrict__ t3) {
  int idx = blockIdx.x * BDIM + threadIdx.x;
  if (idx < 262144) {
    int ox = idx & 63, y = (idx >> 6) & 255, c = idx >> 14;
    float wx[8];
    int x0;
    int n = resize_taps(64, ox, 256, wx, &x0);
    const float* row = a3 + (size_t)c * 65536 + y * 256 + x0;
    float r = 0.f;
    for (int b = 0; b < n; ++b) r += wx[b] * row[b];
    t3[idx] = r;
  } else {
    int j = idx - 262144;
    if (j < 131072) {
      int ox = j & 63, y = (j >> 6) & 127, c = j >> 13;
      float wx[8];
      int x0;
      int n = resize_taps(64, ox, 128, wx, &x0);
      const float* row = a2 + (size_t)c * 16384 + y * 128 + x0;
      float r = 0.f;
      for (int b = 0; b < n; ++b) r += wx[b] * row[b];
      t2[j] = r;
    }
  }
}

__device__ __forceinline__ float gelu_f(float x) {
  return 0.5f * x * (1.f + erff(x * 0.70710678118654752f));
}

// Vertical taps + gelu combine.
__global__ void k_final2(const float* __restrict__ a0, const float* __restrict__ a1,
                         const float* __restrict__ t2, const float* __restrict__ t3,
                         float* __restrict__ out) {
  int i = blockIdx.x * BDIM + threadIdx.x;  // [0, 65536)
  int x = i & 63, y = (i >> 6) & 63, c = i >> 12;
  float x1r = resize_one(a1 + c * 1024, 32, 32, y, x, 64, 64);
  float wv[8];
  int y0;
  int n2 = resize_taps(64, y, 128, wv, &y0);
  const float* tp2 = t2 + (size_t)c * 8192 + y0 * 64 + x;
  float x2r = 0.f;
  for (int a = 0; a < n2; ++a) x2r += wv[a] * tp2[a * 64];
  int n3 = resize_taps(64, y, 256, wv, &y0);
  const float* tp3 = t3 + (size_t)c * 16384 + y0 * 64 + x;
  float x3r = 0.f;
  for (int a = 0; a < n3; ++a) x3r += wv[a] * tp3[a * 64];
  float av = a0[i];
  float l = gelu_f(x1r);
  float m = gelu_f(av - l);
  float h = gelu_f(x2r - av);
  float sv = gelu_f(x3r - x2r);
  out[i] = l;
  out[65536 + i] = m;
  out[131072 + i] = h;
  out[196608 + i] = sv;
}

static inline int cdiv(int a, int b) { return (a + b - 1) / b; }

extern "C" void kernel_launch(void* const* d_in, const int* in_sizes, int n_in,
                              void* d_out, int out_size, void* d_ws, size_t ws_size,
                              hipStream_t stream) {
  (void)in_sizes; (void)n_in; (void)out_size; (void)ws_size;
  const float* x = (const float*)d_in[0];
  const float* w_off[4] = {(const float*)d_in[1], (const float*)d_in[5],
                           (const float*)d_in[9], (const float*)d_in[13]};
  const float* b_off[4] = {(const float*)d_in[2], (const float*)d_in[6],
                           (const float*)d_in[10], (const float*)d_in[14]};
  const float* w_c[4] = {(const float*)d_in[3], (const float*)d_in[7],
                         (const float*)d_in[11], (const float*)d_in[15]};
  const float* b_c[4] = {(const float*)d_in[4], (const float*)d_in[8],
                         (const float*)d_in[12], (const float*)d_in[16]};
  float* out = (float*)d_out;

  // Workspace (floats), lifetime-aliased; peak 7,166,464 f = 28.7 MB.
  float* ws = (float*)d_ws;
  float* a0 = ws;                  // [0, 65536)
  float* a1 = ws + 65536;          // [65536, 81920)
  float* a2 = ws + 81920;          // [81920, 344064)
  float* wT = ws + 344064;         // [344064, 422400)
  float* x1s = ws + 422400;        // [422400, 487936)   dead after k_fused
  float* t3 = ws + 422400;         // ALIAS x1s+ (written post-fused)
  float* t2 = ws + 684544;         // [684544, 815616)
  float* x2s = ws + 875008;        // [875008, 1923584)
  float* x3s = ws + 1923584;       // [1923584, 6117888)
  float* a3 = ws + 6117888;        // [6117888, 7166464)
  float* wTd = wT;                 // 4 x 9216
  float* wTc = wT + 36864;         // 4 x 10368

  FArgs fa;
  const float* ins[4] = {x1s, x, x2s, x3s};
  float* as[4] = {a1, a0, a2, a3};
  for (int s = 0; s < 4; ++s) {
    fa.in[s] = ins[s];
    fa.wc[s] = wTc + s * 10368;
    fa.bc[s] = b_off[s];
    fa.wd[s] = wTd + (3 - s) * 9216;
    fa.bd[s] = b_c[3 - s];
    fa.out[s] = as[s];
  }
  fa.cut0 = 16; fa.cut1 = 80; fa.cut2 = 336;

  k_front<<<cdiv(5386752, BDIM), BDIM, 0, stream>>>(
      x, x1s, x2s, x3s, w_c[0], w_c[1], w_c[2], w_c[3],
      w_off[0], w_off[1], w_off[2], w_off[3], wT);
  k_fused<<<1360, 512, 0, stream>>>(fa);
  k_hpass<<<cdiv(262144 + 131072, BDIM), BDIM, 0, stream>>>(a2, a3, t2, t3);
  k_final2<<<cdiv(65536, BDIM), BDIM, 0, stream>>>(a0, a1, t2, t3, out);
}

// Round 12
// 346.175 us; speedup vs baseline: 2.2081x; 1.2062x over previous
//
#include <hip/hip_runtime.h>
#include <math.h>

#define BDIM 256

// ---------------------------------------------------------------------------
// jax.image.resize (bilinear/triangle, antialias=True) tap weights.
// ---------------------------------------------------------------------------
__device__ __forceinline__ int resize_taps(int out_n, int o, int in_n,
                                           float* w, int* i0) {
  float inv_scale = (float)in_n / (float)out_n;
  float ks = inv_scale > 1.f ? inv_scale : 1.f;
  float sf = ((float)o + 0.5f) * inv_scale - 0.5f;
  int lo = (int)ceilf(sf - ks);
  int hi = (int)floorf(sf + ks);
  if (lo < 0) lo = 0;
  if (hi > in_n - 1) hi = in_n - 1;
  int n = hi - lo + 1;
  float sum = 0.f;
  for (int k = 0; k < n; ++k) {
    float t = 1.f - fabsf((float)(lo + k) - sf) / ks;
    t = t > 0.f ? t : 0.f;
    w[k] = t;
    sum += t;
  }
  float inv = 1.f / sum;
  for (int k = 0; k < n; ++k) w[k] *= inv;
  *i0 = lo;
  return n;
}

__device__ __forceinline__ float resize_one(const float* __restrict__ plane,
                                            int Hi, int Wi, int oy, int ox,
                                            int Ho, int Wo) {
  float wy[8], wx[8];
  int y0, x0;
  int ny = resize_taps(Ho, oy, Hi, wy, &y0);
  int nx = resize_taps(Wo, ox, Wi, wx, &x0);
  float acc = 0.f;
  for (int a = 0; a < ny; ++a) {
    const float* row = plane + (y0 + a) * Wi + x0;
    float r = 0.f;
    for (int b = 0; b < nx; ++b) r += wx[b] * row[b];
    acc += wy[a] * r;
  }
  return acc;
}

// ---------------------------------------------------------------------------
// FRONT kernel: everything that depends only on inputs, one launch.
// ---------------------------------------------------------------------------
__global__ void k_front(const float* __restrict__ x, float* __restrict__ x1s,
                        float* __restrict__ x2s, float* __restrict__ x3s,
                        const float* __restrict__ d0, const float* __restrict__ d1,
                        const float* __restrict__ d2, const float* __restrict__ d3,
                        const float* __restrict__ c0, const float* __restrict__ c1,
                        const float* __restrict__ c2, const float* __restrict__ c3,
                        float* __restrict__ wT) {
  int idx = blockIdx.x * BDIM + threadIdx.x;
  if (idx < 65536) {
    int ox = idx & 31, oy = (idx >> 5) & 31, c = idx >> 10;
    x1s[idx] = resize_one(x + c * 4096, 64, 64, oy, ox, 32, 32);
  } else if (idx < 1114112) {
    int j = idx - 65536;
    int ox = j & 127, oy = (j >> 7) & 127, c = j >> 14;
    x2s[j] = resize_one(x + c * 4096, 64, 64, oy, ox, 128, 128);
  } else if (idx < 5308416) {
    int j = idx - 1114112;
    int ox = j & 255, oy = (j >> 8) & 255, c = j >> 16;
    // x3s = resize(x2s, 256) with x2s values recomputed inline from x
    float wy2[2], wx2[2];
    int ty0, tx0;
    int ny = resize_taps(256, oy, 128, wy2, &ty0);
    int nx = resize_taps(256, ox, 128, wx2, &tx0);
    const float* xc = x + c * 4096;
    float acc = 0.f;
    for (int a = 0; a < ny; ++a)
      for (int b = 0; b < nx; ++b)
        acc += wy2[a] * wx2[b] *
               resize_one(xc, 64, 64, ty0 + a, tx0 + b, 128, 128);
    x3s[j] = acc;
  } else if (idx < 5386752) {
    int w = idx - 5308416;
    if (w < 36864) {
      int i = w / 9216, r = w % 9216;
      int o = r % 16, t = r / 16, c = t % 64, k = t / 64;
      const float* s = i == 0 ? d0 : i == 1 ? d1 : i == 2 ? d2 : d3;
      wT[w] = s[(o * 64 + c) * 9 + k];
    } else {
      int j = w - 36864;
      int i = j / 10368, r = j % 10368;
      int o = r % 18, t = r / 18, c = t % 64, k = t / 64;
      const float* s = i == 0 ? c0 : i == 1 ? c1 : i == 2 ? c2 : c3;
      wT[w] = s[(o * 64 + c) * 9 + k];
    }
  }
}

// ---------------------------------------------------------------------------
// FUSED offset-conv + deformable conv + leaky, all 4 scales in one grid.
// Segments ordered big->small: [0,1024)=scale3, [1024,1280)=scale2,
// [1280,1344)=scale1, [1344,1360)=scale0. Within each segment a bijective
// XCD swizzle (bl&7)*(n/8) + (bl>>3) gives each XCD a contiguous strip range
// so its tap rows fit its private 4MB L2 (consecutive strips share 2/3 rows).
// Block = 512 thr = 8 waves; wave g owns channels [8g,8g+8) for 64 px (lane).
// launch_bounds(512,4): VGPR=64 sweet spot (72 halves occupancy, R11).
// ---------------------------------------------------------------------------
struct FArgs {
  const float* in[4];
  const float* wc[4];   // conv weights [k][c][o18]
  const float* bc[4];   // conv bias
  const float* wd[4];   // deform weights [k][c][o16] (crossed)
  const float* bd[4];   // deform bias (crossed)
  float* out[4];        // a1, a0, a2, a3
};

__global__ __launch_bounds__(512, 4) void k_fused(FArgs A) {
  __shared__ float red[8][64][19];   // 38.9 KB
  int b = blockIdx.x;
  int s, b0, nseg;
  if (b < 1024)      { s = 3; b0 = 0;    nseg = 1024; }
  else if (b < 1280) { s = 2; b0 = 1024; nseg = 256; }
  else if (b < 1344) { s = 1; b0 = 1280; nseg = 64; }
  else               { s = 0; b0 = 1344; nseg = 16; }
  int bl = b - b0;
  int swz = (bl & 7) * (nseg >> 3) + (bl >> 3);
  int H = 32 << s, W = H, lw = 5 + s, HW = H * W;
  int pad = 4 - s, dil = pad;
  const float* in = A.in[s];
  int tid = threadIdx.x, lane = tid & 63;
  int g = __builtin_amdgcn_readfirstlane(tid >> 6);
  int p = swz * 64 + lane;
  int py = p >> lw, px = p & (W - 1);
  const float* ipg = in + (size_t)(g * 8) * HW;

  // ---------------- phase A: offset conv (18 ch), partial over 8 channels
  {
    float accA[18];
#pragma unroll
    for (int o = 0; o < 18; ++o) accA[o] = 0.f;
    const float* wT = A.wc[s];
#pragma unroll
    for (int ky = 0; ky < 3; ++ky) {
#pragma unroll
      for (int kx = 0; kx < 3; ++kx) {
        int k = ky * 3 + kx;
        int yy = py + ky - 1, xx = px + kx - 1;
        float msk = (yy >= 0 && yy < H && xx >= 0 && xx < W) ? 1.f : 0.f;
        int ai = min(max(yy, 0), H - 1) * W + min(max(xx, 0), W - 1);
        const float* ip = ipg + ai;
        const float* wk = wT + (size_t)(k * 64 + g * 8) * 18;
#pragma unroll
        for (int c = 0; c < 8; ++c, ip += HW, wk += 18) {
          float v = *ip * msk;
#pragma unroll
          for (int o = 0; o < 18; ++o) accA[o] += wk[o] * v;
        }
      }
    }
    int gv = tid >> 6;
#pragma unroll
    for (int o = 0; o < 18; ++o) red[gv][lane][o] = accA[o];
  }
  __syncthreads();
  float off[18];
  {
    const float* bc = A.bc[s];
#pragma unroll
    for (int o = 0; o < 18; ++o) {
      float v = bc[o];
#pragma unroll
      for (int r = 0; r < 8; ++r) v += red[r][lane][o];
      off[o] = v;
    }
  }
  __syncthreads();   // all reads of red done before phase-B overwrites

  // ---------------- phase B: deformable conv (16 ch) using off
  float acc[16];
#pragma unroll
  for (int o = 0; o < 16; ++o) acc[o] = 0.f;
  {
    const float* wT = A.wd[s];
#pragma unroll
    for (int ky = 0; ky < 3; ++ky) {
#pragma unroll
      for (int kx = 0; kx < 3; ++kx) {
        int k = ky * 3 + kx;
        float dy = off[2 * k];
        float dx = off[2 * k + 1];
        float pyf = (float)(py - pad + ky * dil) + dy;
        float pxf = (float)(px - pad + kx * dil) + dx;
        float fy0 = floorf(pyf), fx0 = floorf(pxf);
        float wy = pyf - fy0, wxv = pxf - fx0;
        int y0 = (int)fy0, x0 = (int)fx0;
        float xg = (x0 >= -1 && x0 <= W - 1) ? 1.f : 0.f;
        float r0 = (1.f - wy) * ((y0 >= 0 && y0 < H) ? xg : 0.f);
        float r1 = wy * ((y0 + 1 >= 0 && y0 + 1 < H) ? xg : 0.f);
        float cl = 1.f - wxv, cr = wxv;
        bool xlo = x0 < 0, xhi = x0 > W - 2;
        float W00 = xlo ? r0 * cr : (xhi ? 0.f : r0 * cl);
        float W01 = xlo ? 0.f : (xhi ? r0 * cl : r0 * cr);
        float W10 = xlo ? r1 * cr : (xhi ? 0.f : r1 * cl);
        float W11 = xlo ? 0.f : (xhi ? r1 * cl : r1 * cr);
        int ax = min(max(x0, 0), W - 2);
        int cy0 = min(max(y0, 0), H - 1);
        int cy1 = min(max(y0 + 1, 0), H - 1);
        int A0 = cy0 * W + ax, A1 = cy1 * W + ax;
        const float* ip = ipg;
        const float* wk = wT + (size_t)(k * 64 + g * 8) * 16;
#pragma unroll
        for (int c = 0; c < 8; ++c, ip += HW, wk += 16) {
          const float* r0p = ip + A0;
          const float* r1p = ip + A1;
          float sv = W00 * r0p[0] + W01 * r0p[1] + W10 * r1p[0] + W11 * r1p[1];
#pragma unroll
          for (int o = 0; o < 16; ++o) acc[o] += wk[o] * sv;
        }
      }
    }
  }
  int gv = tid >> 6;
  if (gv) {
#pragma unroll
    for (int o = 0; o < 16; ++o) red[gv - 1][lane][o] = acc[o];
  }
  __syncthreads();
  if (!gv) {
    const float* bd = A.bd[s];
    float* out = A.out[s];
#pragma unroll
    for (int o = 0; o < 16; ++o) {
      float v = acc[o] + bd[o];
#pragma unroll
      for (int r = 0; r < 7; ++r) v += red[r][lane][o];
      v = v >= 0.f ? v : 0.01f * v;
      out[(size_t)o * HW + p] = v;
    }
  }
}

// ---------------------------------------------------------------------------
// Horizontal downsample pass: a3 (16,256,256) -> t3 (16,256,64) 8 taps;
// a2 (16,128,128) -> t2 (16,128,64) 4 taps.
// ---------------------------------------------------------------------------
__global__ void k_hpass(const float* __restrict__ a2, const float* __restrict__ a3,
                        float* __restrict__ t2, float* __restrict__ t3) {
  int idx = blockIdx.x * BDIM + threadIdx.x;
  if (idx < 262144) {
    int ox = idx & 63, y = (idx >> 6) & 255, c = idx >> 14;
    float wx[8];
    int x0;
    int n = resize_taps(64, ox, 256, wx, &x0);
    const float* row = a3 + (size_t)c * 65536 + y * 256 + x0;
    float r = 0.f;
    for (int b = 0; b < n; ++b) r += wx[b] * row[b];
    t3[idx] = r;
  } else {
    int j = idx - 262144;
    if (j < 131072) {
      int ox = j & 63, y = (j >> 6) & 127, c = j >> 13;
      float wx[8];
      int x0;
      int n = resize_taps(64, ox, 128, wx, &x0);
      const float* row = a2 + (size_t)c * 16384 + y * 128 + x0;
      float r = 0.f;
      for (int b = 0; b < n; ++b) r += wx[b] * row[b];
      t2[j] = r;
    }
  }
}

__device__ __forceinline__ float gelu_f(float x) {
  return 0.5f * x * (1.f + erff(x * 0.70710678118654752f));
}

// Vertical taps + gelu combine.
__global__ void k_final2(const float* __restrict__ a0, const float* __restrict__ a1,
                         const float* __restrict__ t2, const float* __restrict__ t3,
                         float* __restrict__ out) {
  int i = blockIdx.x * BDIM + threadIdx.x;  // [0, 65536)
  int x = i & 63, y = (i >> 6) & 63, c = i >> 12;
  float x1r = resize_one(a1 + c * 1024, 32, 32, y, x, 64, 64);
  float wv[8];
  int y0;
  int n2 = resize_taps(64, y, 128, wv, &y0);
  const float* tp2 = t2 + (size_t)c * 8192 + y0 * 64 + x;
  float x2r = 0.f;
  for (int a = 0; a < n2; ++a) x2r += wv[a] * tp2[a * 64];
  int n3 = resize_taps(64, y, 256, wv, &y0);
  const float* tp3 = t3 + (size_t)c * 16384 + y0 * 64 + x;
  float x3r = 0.f;
  for (int a = 0; a < n3; ++a) x3r += wv[a] * tp3[a * 64];
  float av = a0[i];
  float l = gelu_f(x1r);
  float m = gelu_f(av - l);
  float h = gelu_f(x2r - av);
  float sv = gelu_f(x3r - x2r);
  out[i] = l;
  out[65536 + i] = m;
  out[131072 + i] = h;
  out[196608 + i] = sv;
}

static inline int cdiv(int a, int b) { return (a + b - 1) / b; }

extern "C" void kernel_launch(void* const* d_in, const int* in_sizes, int n_in,
                              void* d_out, int out_size, void* d_ws, size_t ws_size,
                              hipStream_t stream) {
  (void)in_sizes; (void)n_in; (void)out_size; (void)ws_size;
  const float* x = (const float*)d_in[0];
  const float* w_off[4] = {(const float*)d_in[1], (const float*)d_in[5],
                           (const float*)d_in[9], (const float*)d_in[13]};
  const float* b_off[4] = {(const float*)d_in[2], (const float*)d_in[6],
                           (const float*)d_in[10], (const float*)d_in[14]};
  const float* w_c[4] = {(const float*)d_in[3], (const float*)d_in[7],
                         (const float*)d_in[11], (const float*)d_in[15]};
  const float* b_c[4] = {(const float*)d_in[4], (const float*)d_in[8],
                         (const float*)d_in[12], (const float*)d_in[16]};
  float* out = (float*)d_out;

  // Workspace (floats), lifetime-aliased; peak 7,166,464 f = 28.7 MB.
  float* ws = (float*)d_ws;
  float* a0 = ws;                  // [0, 65536)
  float* a1 = ws + 65536;          // [65536, 81920)
  float* a2 = ws + 81920;          // [81920, 344064)
  float* wT = ws + 344064;         // [344064, 422400)
  float* x1s = ws + 422400;        // [422400, 487936)   dead after k_fused
  float* t3 = ws + 422400;         // ALIAS x1s+ (written post-fused)
  float* t2 = ws + 684544;         // [684544, 815616)
  float* x2s = ws + 875008;        // [875008, 1923584)
  float* x3s = ws + 1923584;       // [1923584, 6117888)
  float* a3 = ws + 6117888;        // [6117888, 7166464)
  float* wTd = wT;                 // 4 x 9216
  float* wTc = wT + 36864;         // 4 x 10368

  FArgs fa;
  const float* ins[4] = {x1s, x, x2s, x3s};
  float* as[4] = {a1, a0, a2, a3};
  for (int s = 0; s < 4; ++s) {
    fa.in[s] = ins[s];
    fa.wc[s] = wTc + s * 10368;
    fa.bc[s] = b_off[s];
    fa.wd[s] = wTd + (3 - s) * 9216;
    fa.bd[s] = b_c[3 - s];
    fa.out[s] = as[s];
  }

  k_front<<<cdiv(5386752, BDIM), BDIM, 0, stream>>>(
      x, x1s, x2s, x3s, w_c[0], w_c[1], w_c[2], w_c[3],
      w_off[0], w_off[1], w_off[2], w_off[3], wT);
  k_fused<<<1360, 512, 0, stream>>>(fa);
  k_hpass<<<cdiv(262144 + 131072, BDIM), BDIM, 0, stream>>>(a2, a3, t2, t3);
  k_final2<<<cdiv(65536, BDIM), BDIM, 0, stream>>>(a0, a1, t2, t3, out);
}

// Round 13
// 233.717 us; speedup vs baseline: 3.2705x; 1.4812x over previous
//
#include <hip/hip_runtime.h>
#include <math.h>

#define BDIM 256

// ---------------------------------------------------------------------------
// jax.image.resize (bilinear/triangle, antialias=True) tap weights.
// ---------------------------------------------------------------------------
__device__ __forceinline__ int resize_taps(int out_n, int o, int in_n,
                                           float* w, int* i0) {
  float inv_scale = (float)in_n / (float)out_n;
  float ks = inv_scale > 1.f ? inv_scale : 1.f;
  float sf = ((float)o + 0.5f) * inv_scale - 0.5f;
  int lo = (int)ceilf(sf - ks);
  int hi = (int)floorf(sf + ks);
  if (lo < 0) lo = 0;
  if (hi > in_n - 1) hi = in_n - 1;
  int n = hi - lo + 1;
  float sum = 0.f;
  for (int k = 0; k < n; ++k) {
    float t = 1.f - fabsf((float)(lo + k) - sf) / ks;
    t = t > 0.f ? t : 0.f;
    w[k] = t;
    sum += t;
  }
  float inv = 1.f / sum;
  for (int k = 0; k < n; ++k) w[k] *= inv;
  *i0 = lo;
  return n;
}

__device__ __forceinline__ float resize_one(const float* __restrict__ plane,
                                            int Hi, int Wi, int oy, int ox,
                                            int Ho, int Wo) {
  float wy[8], wx[8];
  int y0, x0;
  int ny = resize_taps(Ho, oy, Hi, wy, &y0);
  int nx = resize_taps(Wo, ox, Wi, wx, &x0);
  float acc = 0.f;
  for (int a = 0; a < ny; ++a) {
    const float* row = plane + (y0 + a) * Wi + x0;
    float r = 0.f;
    for (int b = 0; b < nx; ++b) r += wx[b] * row[b];
    acc += wy[a] * r;
  }
  return acc;
}

// ---------------------------------------------------------------------------
// Front 1: x1s (64->32), x2s (64->128), weight transpose. One launch.
// ---------------------------------------------------------------------------
__global__ void k_front(const float* __restrict__ x, float* __restrict__ x1s,
                        float* __restrict__ x2s,
                        const float* __restrict__ d0, const float* __restrict__ d1,
                        const float* __restrict__ d2, const float* __restrict__ d3,
                        const float* __restrict__ c0, const float* __restrict__ c1,
                        const float* __restrict__ c2, const float* __restrict__ c3,
                        float* __restrict__ wT) {
  int idx = blockIdx.x * BDIM + threadIdx.x;
  if (idx < 65536) {
    int ox = idx & 31, oy = (idx >> 5) & 31, c = idx >> 10;
    x1s[idx] = resize_one(x + c * 4096, 64, 64, oy, ox, 32, 32);
  } else if (idx < 1114112) {
    int j = idx - 65536;
    int ox = j & 127, oy = (j >> 7) & 127, c = j >> 14;
    x2s[j] = resize_one(x + c * 4096, 64, 64, oy, ox, 128, 128);
  } else if (idx < 1192448) {
    int w = idx - 1114112;
    if (w < 36864) {
      int i = w / 9216, r = w % 9216;
      int o = r % 16, t = r / 16, c = t % 64, k = t / 64;
      const float* s = i == 0 ? d0 : i == 1 ? d1 : i == 2 ? d2 : d3;
      wT[w] = s[(o * 64 + c) * 9 + k];
    } else {
      int j = w - 36864;
      int i = j / 10368, r = j % 10368;
      int o = r % 18, t = r / 18, c = t % 64, k = t / 64;
      const float* s = i == 0 ? c0 : i == 1 ? c1 : i == 2 ? c2 : c3;
      wT[w] = s[(o * 64 + c) * 9 + k];
    }
  }
}

// Front 2: x3s = resize(x2s, 128->256). Memory-bound 2x2-tap upsample.
__global__ void k_up3(const float* __restrict__ x2s, float* __restrict__ x3s) {
  int idx = blockIdx.x * BDIM + threadIdx.x;
  if (idx >= 64 * 256 * 256) return;
  int ox = idx & 255, oy = (idx >> 8) & 255, c = idx >> 16;
  x3s[idx] = resize_one(x2s + (size_t)c * 16384, 128, 128, oy, ox, 256, 256);
}

// ---------------------------------------------------------------------------
// FUSED offset-conv + deformable conv + leaky, all 4 scales in one grid.
// Segments big->small; per-segment bijective XCD swizzle (bl&7)*(n/8)+(bl>>3)
// gives each XCD a contiguous strip range (tap rows fit its private 4MB L2).
// Block = 512 thr = 8 waves; wave g owns channels [8g,8g+8) for 64 px (lane).
// launch_bounds(512,4): VGPR=64 sweet spot (72 halves occupancy, R11).
// ---------------------------------------------------------------------------
struct FArgs {
  const float* in[4];
  const float* wc[4];   // conv weights [k][c][o18]
  const float* bc[4];   // conv bias
  const float* wd[4];   // deform weights [k][c][o16] (crossed)
  const float* bd[4];   // deform bias (crossed)
  float* out[4];        // a1, a0, a2, a3
};

__global__ __launch_bounds__(512, 4) void k_fused(FArgs A) {
  __shared__ float red[8][64][19];   // 38.9 KB
  int b = blockIdx.x;
  int s, b0, nseg;
  if (b < 1024)      { s = 3; b0 = 0;    nseg = 1024; }
  else if (b < 1280) { s = 2; b0 = 1024; nseg = 256; }
  else if (b < 1344) { s = 1; b0 = 1280; nseg = 64; }
  else               { s = 0; b0 = 1344; nseg = 16; }
  int bl = b - b0;
  int swz = (bl & 7) * (nseg >> 3) + (bl >> 3);
  int H = 32 << s, W = H, lw = 5 + s, HW = H * W;
  int pad = 4 - s, dil = pad;
  const float* in = A.in[s];
  int tid = threadIdx.x, lane = tid & 63;
  int g = __builtin_amdgcn_readfirstlane(tid >> 6);
  int p = swz * 64 + lane;
  int py = p >> lw, px = p & (W - 1);
  const float* ipg = in + (size_t)(g * 8) * HW;

  // ---------------- phase A: offset conv (18 ch), partial over 8 channels
  {
    float accA[18];
#pragma unroll
    for (int o = 0; o < 18; ++o) accA[o] = 0.f;
    const float* wT = A.wc[s];
#pragma unroll
    for (int ky = 0; ky < 3; ++ky) {
#pragma unroll
      for (int kx = 0; kx < 3; ++kx) {
        int k = ky * 3 + kx;
        int yy = py + ky - 1, xx = px + kx - 1;
        float msk = (yy >= 0 && yy < H && xx >= 0 && xx < W) ? 1.f : 0.f;
        int ai = min(max(yy, 0), H - 1) * W + min(max(xx, 0), W - 1);
        const float* ip = ipg + ai;
        const float* wk = wT + (size_t)(k * 64 + g * 8) * 18;
#pragma unroll
        for (int c = 0; c < 8; ++c, ip += HW, wk += 18) {
          float v = *ip * msk;
#pragma unroll
          for (int o = 0; o < 18; ++o) accA[o] += wk[o] * v;
        }
      }
    }
    int gv = tid >> 6;
#pragma unroll
    for (int o = 0; o < 18; ++o) red[gv][lane][o] = accA[o];
  }
  __syncthreads();
  float off[18];
  {
    const float* bc = A.bc[s];
#pragma unroll
    for (int o = 0; o < 18; ++o) {
      float v = bc[o];
#pragma unroll
      for (int r = 0; r < 8; ++r) v += red[r][lane][o];
      off[o] = v;
    }
  }
  __syncthreads();   // all reads of red done before phase-B overwrites

  // ---------------- phase B: deformable conv (16 ch) using off
  float acc[16];
#pragma unroll
  for (int o = 0; o < 16; ++o) acc[o] = 0.f;
  {
    const float* wT = A.wd[s];
#pragma unroll
    for (int ky = 0; ky < 3; ++ky) {
#pragma unroll
      for (int kx = 0; kx < 3; ++kx) {
        int k = ky * 3 + kx;
        float dy = off[2 * k];
        float dx = off[2 * k + 1];
        float pyf = (float)(py - pad + ky * dil) + dy;
        float pxf = (float)(px - pad + kx * dil) + dx;
        float fy0 = floorf(pyf), fx0 = floorf(pxf);
        float wy = pyf - fy0, wxv = pxf - fx0;
        int y0 = (int)fy0, x0 = (int)fx0;
        float xg = (x0 >= -1 && x0 <= W - 1) ? 1.f : 0.f;
        float r0 = (1.f - wy) * ((y0 >= 0 && y0 < H) ? xg : 0.f);
        float r1 = wy * ((y0 + 1 >= 0 && y0 + 1 < H) ? xg : 0.f);
        float cl = 1.f - wxv, cr = wxv;
        bool xlo = x0 < 0, xhi = x0 > W - 2;
        float W00 = xlo ? r0 * cr : (xhi ? 0.f : r0 * cl);
        float W01 = xlo ? 0.f : (xhi ? r0 * cl : r0 * cr);
        float W10 = xlo ? r1 * cr : (xhi ? 0.f : r1 * cl);
        float W11 = xlo ? 0.f : (xhi ? r1 * cl : r1 * cr);
        int ax = min(max(x0, 0), W - 2);
        int cy0 = min(max(y0, 0), H - 1);
        int cy1 = min(max(y0 + 1, 0), H - 1);
        int A0 = cy0 * W + ax, A1 = cy1 * W + ax;
        const float* ip = ipg;
        const float* wk = wT + (size_t)(k * 64 + g * 8) * 16;
#pragma unroll
        for (int c = 0; c < 8; ++c, ip += HW, wk += 16) {
          const float* r0p = ip + A0;
          const float* r1p = ip + A1;
          float sv = W00 * r0p[0] + W01 * r0p[1] + W10 * r1p[0] + W11 * r1p[1];
#pragma unroll
          for (int o = 0; o < 16; ++o) acc[o] += wk[o] * sv;
        }
      }
    }
  }
  int gv = tid >> 6;
  if (gv) {
#pragma unroll
    for (int o = 0; o < 16; ++o) red[gv - 1][lane][o] = acc[o];
  }
  __syncthreads();
  if (!gv) {
    const float* bd = A.bd[s];
    float* out = A.out[s];
#pragma unroll
    for (int o = 0; o < 16; ++o) {
      float v = acc[o] + bd[o];
#pragma unroll
      for (int r = 0; r < 7; ++r) v += red[r][lane][o];
      v = v >= 0.f ? v : 0.01f * v;
      out[(size_t)o * HW + p] = v;
    }
  }
}

// ---------------------------------------------------------------------------
// Horizontal downsample pass: a3 (16,256,256) -> t3 (16,256,64) 8 taps;
// a2 (16,128,128) -> t2 (16,128,64) 4 taps.
// ---------------------------------------------------------------------------
__global__ void k_hpass(const float* __restrict__ a2, const float* __restrict__ a3,
                        float* __restrict__ t2, float* __restrict__ t3) {
  int idx = blockIdx.x * BDIM + threadIdx.x;
  if (idx < 262144) {
    int ox = idx & 63, y = (idx >> 6) & 255, c = idx >> 14;
    float wx[8];
    int x0;
    int n = resize_taps(64, ox, 256, wx, &x0);
    const float* row = a3 + (size_t)c * 65536 + y * 256 + x0;
    float r = 0.f;
    for (int b = 0; b < n; ++b) r += wx[b] * row[b];
    t3[idx] = r;
  } else {
    int j = idx - 262144;
    if (j < 131072) {
      int ox = j & 63, y = (j >> 6) & 127, c = j >> 13;
      float wx[8];
      int x0;
      int n = resize_taps(64, ox, 128, wx, &x0);
      const float* row = a2 + (size_t)c * 16384 + y * 128 + x0;
      float r = 0.f;
      for (int b = 0; b < n; ++b) r += wx[b] * row[b];
      t2[j] = r;
    }
  }
}

__device__ __forceinline__ float gelu_f(float x) {
  return 0.5f * x * (1.f + erff(x * 0.70710678118654752f));
}

// Vertical taps + gelu combine.
__global__ void k_final2(const float* __restrict__ a0, const float* __restrict__ a1,
                         const float* __restrict__ t2, const float* __restrict__ t3,
                         float* __restrict__ out) {
  int i = blockIdx.x * BDIM + threadIdx.x;  // [0, 65536)
  int x = i & 63, y = (i >> 6) & 63, c = i >> 12;
  float x1r = resize_one(a1 + c * 1024, 32, 32, y, x, 64, 64);
  float wv[8];
  int y0;
  int n2 = resize_taps(64, y, 128, wv, &y0);
  const float* tp2 = t2 + (size_t)c * 8192 + y0 * 64 + x;
  float x2r = 0.f;
  for (int a = 0; a < n2; ++a) x2r += wv[a] * tp2[a * 64];
  int n3 = resize_taps(64, y, 256, wv, &y0);
  const float* tp3 = t3 + (size_t)c * 16384 + y0 * 64 + x;
  float x3r = 0.f;
  for (int a = 0; a < n3; ++a) x3r += wv[a] * tp3[a * 64];
  float av = a0[i];
  float l = gelu_f(x1r);
  float m = gelu_f(av - l);
  float h = gelu_f(x2r - av);
  float sv = gelu_f(x3r - x2r);
  out[i] = l;
  out[65536 + i] = m;
  out[131072 + i] = h;
  out[196608 + i] = sv;
}

static inline int cdiv(int a, int b) { return (a + b - 1) / b; }

extern "C" void kernel_launch(void* const* d_in, const int* in_sizes, int n_in,
                              void* d_out, int out_size, void* d_ws, size_t ws_size,
                              hipStream_t stream) {
  (void)in_sizes; (void)n_in; (void)out_size; (void)ws_size;
  const float* x = (const float*)d_in[0];
  const float* w_off[4] = {(const float*)d_in[1], (const float*)d_in[5],
                           (const float*)d_in[9], (const float*)d_in[13]};
  const float* b_off[4] = {(const float*)d_in[2], (const float*)d_in[6],
                           (const float*)d_in[10], (const float*)d_in[14]};
  const float* w_c[4] = {(const float*)d_in[3], (const float*)d_in[7],
                         (const float*)d_in[11], (const float*)d_in[15]};
  const float* b_c[4] = {(const float*)d_in[4], (const float*)d_in[8],
                         (const float*)d_in[12], (const float*)d_in[16]};
  float* out = (float*)d_out;

  // Workspace (floats), lifetime-aliased; peak 7,166,464 f = 28.7 MB.
  float* ws = (float*)d_ws;
  float* a0 = ws;                  // [0, 65536)
  float* a1 = ws + 65536;          // [65536, 81920)
  float* a2 = ws + 81920;          // [81920, 344064)
  float* wT = ws + 344064;         // [344064, 422400)
  float* x1s = ws + 422400;        // [422400, 487936)   dead after k_fused
  float* t3 = ws + 422400;         // ALIAS x1s+ (written post-fused)
  float* t2 = ws + 684544;         // [684544, 815616)
  float* x2s = ws + 875008;        // [875008, 1923584)
  float* x3s = ws + 1923584;       // [1923584, 6117888)
  float* a3 = ws + 6117888;        // [6117888, 7166464)
  float* wTd = wT;                 // 4 x 9216
  float* wTc = wT + 36864;         // 4 x 10368

  FArgs fa;
  const float* ins[4] = {x1s, x, x2s, x3s};
  float* as[4] = {a1, a0, a2, a3};
  for (int s = 0; s < 4; ++s) {
    fa.in[s] = ins[s];
    fa.wc[s] = wTc + s * 10368;
    fa.bc[s] = b_off[s];
    fa.wd[s] = wTd + (3 - s) * 9216;
    fa.bd[s] = b_c[3 - s];
    fa.out[s] = as[s];
  }

  k_front<<<cdiv(1192448, BDIM), BDIM, 0, stream>>>(
      x, x1s, x2s, w_c[0], w_c[1], w_c[2], w_c[3],
      w_off[0], w_off[1], w_off[2], w_off[3], wT);
  k_up3<<<cdiv(64 * 256 * 256, BDIM), BDIM, 0, stream>>>(x2s, x3s);
  k_fused<<<1360, 512, 0, stream>>>(fa);
  k_hpass<<<cdiv(262144 + 131072, BDIM), BDIM, 0, stream>>>(a2, a3, t2, t3);
  k_final2<<<cdiv(65536, BDIM), BDIM, 0, stream>>>(a0, a1, t2, t3, out);
}

// Round 14
// 221.295 us; speedup vs baseline: 3.4541x; 1.0561x over previous
//
#include <hip/hip_runtime.h>
#include <math.h>

#define BDIM 256

typedef float v2f __attribute__((ext_vector_type(2)));

__device__ __forceinline__ v2f pkfma(v2f a, v2f b, v2f c) {
#if __has_builtin(__builtin_elementwise_fma)
  return __builtin_elementwise_fma(a, b, c);
#else
  v2f d;
  d.x = fmaf(a.x, b.x, c.x);
  d.y = fmaf(a.y, b.y, c.y);
  return d;
#endif
}

// ---------------------------------------------------------------------------
// jax.image.resize (bilinear/triangle, antialias=True) tap weights.
// ---------------------------------------------------------------------------
__device__ __forceinline__ int resize_taps(int out_n, int o, int in_n,
                                           float* w, int* i0) {
  float inv_scale = (float)in_n / (float)out_n;
  float ks = inv_scale > 1.f ? inv_scale : 1.f;
  float sf = ((float)o + 0.5f) * inv_scale - 0.5f;
  int lo = (int)ceilf(sf - ks);
  int hi = (int)floorf(sf + ks);
  if (lo < 0) lo = 0;
  if (hi > in_n - 1) hi = in_n - 1;
  int n = hi - lo + 1;
  float sum = 0.f;
  for (int k = 0; k < n; ++k) {
    float t = 1.f - fabsf((float)(lo + k) - sf) / ks;
    t = t > 0.f ? t : 0.f;
    w[k] = t;
    sum += t;
  }
  float inv = 1.f / sum;
  for (int k = 0; k < n; ++k) w[k] *= inv;
  *i0 = lo;
  return n;
}

__device__ __forceinline__ float resize_one(const float* __restrict__ plane,
                                            int Hi, int Wi, int oy, int ox,
                                            int Ho, int Wo) {
  float wy[8], wx[8];
  int y0, x0;
  int ny = resize_taps(Ho, oy, Hi, wy, &y0);
  int nx = resize_taps(Wo, ox, Wi, wx, &x0);
  float acc = 0.f;
  for (int a = 0; a < ny; ++a) {
    const float* row = plane + (y0 + a) * Wi + x0;
    float r = 0.f;
    for (int b = 0; b < nx; ++b) r += wx[b] * row[b];
    acc += wy[a] * r;
  }
  return acc;
}

// ---------------------------------------------------------------------------
// Front 1: x1s (64->32), x2s (64->128), weight transpose. One launch.
// ---------------------------------------------------------------------------
__global__ void k_front(const float* __restrict__ x, float* __restrict__ x1s,
                        float* __restrict__ x2s,
                        const float* __restrict__ d0, const float* __restrict__ d1,
                        const float* __restrict__ d2, const float* __restrict__ d3,
                        const float* __restrict__ c0, const float* __restrict__ c1,
                        const float* __restrict__ c2, const float* __restrict__ c3,
                        float* __restrict__ wT) {
  int idx = blockIdx.x * BDIM + threadIdx.x;
  if (idx < 65536) {
    int ox = idx & 31, oy = (idx >> 5) & 31, c = idx >> 10;
    x1s[idx] = resize_one(x + c * 4096, 64, 64, oy, ox, 32, 32);
  } else if (idx < 1114112) {
    int j = idx - 65536;
    int ox = j & 127, oy = (j >> 7) & 127, c = j >> 14;
    x2s[j] = resize_one(x + c * 4096, 64, 64, oy, ox, 128, 128);
  } else if (idx < 1192448) {
    int w = idx - 1114112;
    if (w < 36864) {
      int i = w / 9216, r = w % 9216;
      int o = r % 16, t = r / 16, c = t % 64, k = t / 64;
      const float* s = i == 0 ? d0 : i == 1 ? d1 : i == 2 ? d2 : d3;
      wT[w] = s[(o * 64 + c) * 9 + k];
    } else {
      int j = w - 36864;
      int i = j / 10368, r = j % 10368;
      int o = r % 18, t = r / 18, c = t % 64, k = t / 64;
      const float* s = i == 0 ? c0 : i == 1 ? c1 : i == 2 ? c2 : c3;
      wT[w] = s[(o * 64 + c) * 9 + k];
    }
  }
}

// Front 2: x3s = resize(x2s, 128->256). Memory-bound 2x2-tap upsample.
__global__ void k_up3(const float* __restrict__ x2s, float* __restrict__ x3s) {
  int idx = blockIdx.x * BDIM + threadIdx.x;
  if (idx >= 64 * 256 * 256) return;
  int ox = idx & 255, oy = (idx >> 8) & 255, c = idx >> 16;
  x3s[idx] = resize_one(x2s + (size_t)c * 16384, 128, 128, oy, ox, 256, 256);
}

// ---------------------------------------------------------------------------
// FUSED offset-conv + deformable conv + leaky, all 4 scales in one grid.
// Segments big->small; per-segment bijective XCD swizzle (bl&7)*(n/8)+(bl>>3).
// Block = 512 thr = 8 waves; wave g owns channels [8g,8g+8) for 64 px (lane).
// Inner loops use v2f packed math (v_pk_fma_f32 on CDNA): one inst = 2 FMAs.
// launch_bounds(512,4): VGPR=64 sweet spot (>64 halves occupancy, R11).
// ---------------------------------------------------------------------------
struct FArgs {
  const float* in[4];
  const float* wc[4];   // conv weights [k][c][o18]
  const float* bc[4];   // conv bias
  const float* wd[4];   // deform weights [k][c][o16] (crossed)
  const float* bd[4];   // deform bias (crossed)
  float* out[4];        // a1, a0, a2, a3
};

__global__ __launch_bounds__(512, 4) void k_fused(FArgs A) {
  __shared__ float red[8 * 64 * 18];   // 36 KB, stride 18 (2-way = free)
  int b = blockIdx.x;
  int s, b0, nseg;
  if (b < 1024)      { s = 3; b0 = 0;    nseg = 1024; }
  else if (b < 1280) { s = 2; b0 = 1024; nseg = 256; }
  else if (b < 1344) { s = 1; b0 = 1280; nseg = 64; }
  else               { s = 0; b0 = 1344; nseg = 16; }
  int bl = b - b0;
  int swz = (bl & 7) * (nseg >> 3) + (bl >> 3);
  int H = 32 << s, W = H, lw = 5 + s, HW = H * W;
  int pad = 4 - s, dil = pad;
  const float* in = A.in[s];
  int tid = threadIdx.x, lane = tid & 63;
  int gv = tid >> 6;
  int g = __builtin_amdgcn_readfirstlane(gv);
  int p = swz * 64 + lane;
  int py = p >> lw, px = p & (W - 1);
  const float* ipg = in + (size_t)(g * 8) * HW;
  float* myred = &red[(size_t)(gv * 64 + lane) * 18];
  const float* lred = &red[lane * 18];

  // ---------------- phase A: offset conv (18 ch), partial over 8 channels
  {
    v2f accA[9];
#pragma unroll
    for (int j = 0; j < 9; ++j) accA[j] = (v2f){0.f, 0.f};
    const float* wT = A.wc[s];
#pragma unroll
    for (int ky = 0; ky < 3; ++ky) {
#pragma unroll
      for (int kx = 0; kx < 3; ++kx) {
        int k = ky * 3 + kx;
        int yy = py + ky - 1, xx = px + kx - 1;
        float msk = (yy >= 0 && yy < H && xx >= 0 && xx < W) ? 1.f : 0.f;
        int ai = min(max(yy, 0), H - 1) * W + min(max(xx, 0), W - 1);
        const float* ip = ipg + ai;
        const v2f* wk2 = (const v2f*)(wT + (size_t)(k * 64 + g * 8) * 18);
#pragma unroll
        for (int c = 0; c < 8; ++c, ip += HW, wk2 += 9) {
          float v = *ip * msk;
          v2f vv = {v, v};
#pragma unroll
          for (int j = 0; j < 9; ++j) accA[j] = pkfma(wk2[j], vv, accA[j]);
        }
      }
    }
#pragma unroll
    for (int j = 0; j < 9; ++j) *(v2f*)(myred + 2 * j) = accA[j];
  }
  __syncthreads();
  v2f off2[9];
  {
    const v2f* bc2 = (const v2f*)A.bc[s];
#pragma unroll
    for (int j = 0; j < 9; ++j) {
      v2f v = bc2[j];
#pragma unroll
      for (int r = 0; r < 8; ++r) v += *(const v2f*)(lred + (size_t)r * 64 * 18 + 2 * j);
      off2[j] = v;
    }
  }
  __syncthreads();   // all reads of red done before phase-B overwrites

  // ---------------- phase B: deformable conv (16 ch) using off2
  v2f acc2[8];
#pragma unroll
  for (int j = 0; j < 8; ++j) acc2[j] = (v2f){0.f, 0.f};
  {
    const float* wT = A.wd[s];
#pragma unroll
    for (int ky = 0; ky < 3; ++ky) {
#pragma unroll
      for (int kx = 0; kx < 3; ++kx) {
        int k = ky * 3 + kx;
        float dy = off2[k].x;
        float dx = off2[k].y;
        float pyf = (float)(py - pad + ky * dil) + dy;
        float pxf = (float)(px - pad + kx * dil) + dx;
        float fy0 = floorf(pyf), fx0 = floorf(pxf);
        float wy = pyf - fy0, wxv = pxf - fx0;
        int y0 = (int)fy0, x0 = (int)fx0;
        float xg = (x0 >= -1 && x0 <= W - 1) ? 1.f : 0.f;
        float r0 = (1.f - wy) * ((y0 >= 0 && y0 < H) ? xg : 0.f);
        float r1 = wy * ((y0 + 1 >= 0 && y0 + 1 < H) ? xg : 0.f);
        float cl = 1.f - wxv, cr = wxv;
        bool xlo = x0 < 0, xhi = x0 > W - 2;
        float W00 = xlo ? r0 * cr : (xhi ? 0.f : r0 * cl);
        float W01 = xlo ? 0.f : (xhi ? r0 * cl : r0 * cr);
        float W10 = xlo ? r1 * cr : (xhi ? 0.f : r1 * cl);
        float W11 = xlo ? 0.f : (xhi ? r1 * cl : r1 * cr);
        int ax = min(max(x0, 0), W - 2);
        int cy0 = min(max(y0, 0), H - 1);
        int cy1 = min(max(y0 + 1, 0), H - 1);
        int A0 = cy0 * W + ax, A1 = cy1 * W + ax;
        const float* ip = ipg;
        const v2f* wk2 = (const v2f*)(wT + (size_t)(k * 64 + g * 8) * 16);
#pragma unroll
        for (int c = 0; c < 8; ++c, ip += HW, wk2 += 8) {
          const float* r0p = ip + A0;
          const float* r1p = ip + A1;
          float sv = W00 * r0p[0] + W01 * r0p[1] + W10 * r1p[0] + W11 * r1p[1];
          v2f vv = {sv, sv};
#pragma unroll
          for (int j = 0; j < 8; ++j) acc2[j] = pkfma(wk2[j], vv, acc2[j]);
        }
      }
    }
  }
  if (gv) {
    float* wr = &red[(size_t)((gv - 1) * 64 + lane) * 18];
#pragma unroll
    for (int j = 0; j < 8; ++j) *(v2f*)(wr + 2 * j) = acc2[j];
  }
  __syncthreads();
  if (!gv) {
    const v2f* bd2 = (const v2f*)A.bd[s];
    float* out = A.out[s];
#pragma unroll
    for (int j = 0; j < 8; ++j) {
      v2f v = acc2[j] + bd2[j];
#pragma unroll
      for (int r = 0; r < 7; ++r) v += *(const v2f*)(lred + (size_t)r * 64 * 18 + 2 * j);
      float vx = v.x, vy = v.y;
      vx = vx >= 0.f ? vx : 0.01f * vx;
      vy = vy >= 0.f ? vy : 0.01f * vy;
      out[(size_t)(2 * j) * HW + p] = vx;
      out[(size_t)(2 * j + 1) * HW + p] = vy;
    }
  }
}

// ---------------------------------------------------------------------------
// Horizontal downsample pass: a3 (16,256,256) -> t3 (16,256,64) 8 taps;
// a2 (16,128,128) -> t2 (16,128,64) 4 taps.
// ---------------------------------------------------------------------------
__global__ void k_hpass(const float* __restrict__ a2, const float* __restrict__ a3,
                        float* __restrict__ t2, float* __restrict__ t3) {
  int idx = blockIdx.x * BDIM + threadIdx.x;
  if (idx < 262144) {
    int ox = idx & 63, y = (idx >> 6) & 255, c = idx >> 14;
    float wx[8];
    int x0;
    int n = resize_taps(64, ox, 256, wx, &x0);
    const float* row = a3 + (size_t)c * 65536 + y * 256 + x0;
    float r = 0.f;
    for (int b = 0; b < n; ++b) r += wx[b] * row[b];
    t3[idx] = r;
  } else {
    int j = idx - 262144;
    if (j < 131072) {
      int ox = j & 63, y = (j >> 6) & 127, c = j >> 13;
      float wx[8];
      int x0;
      int n = resize_taps(64, ox, 128, wx, &x0);
      const float* row = a2 + (size_t)c * 16384 + y * 128 + x0;
      float r = 0.f;
      for (int b = 0; b < n; ++b) r += wx[b] * row[b];
      t2[j] = r;
    }
  }
}

__device__ __forceinline__ float gelu_f(float x) {
  return 0.5f * x * (1.f + erff(x * 0.70710678118654752f));
}

// Vertical taps + gelu combine.
__global__ void k_final2(const float* __restrict__ a0, const float* __restrict__ a1,
                         const float* __restrict__ t2, const float* __restrict__ t3,
                         float* __restrict__ out) {
  int i = blockIdx.x * BDIM + threadIdx.x;  // [0, 65536)
  int x = i & 63, y = (i >> 6) & 63, c = i >> 12;
  float x1r = resize_one(a1 + c * 1024, 32, 32, y, x, 64, 64);
  float wv[8];
  int y0;
  int n2 = resize_taps(64, y, 128, wv, &y0);
  const float* tp2 = t2 + (size_t)c * 8192 + y0 * 64 + x;
  float x2r = 0.f;
  for (int a = 0; a < n2; ++a) x2r += wv[a] * tp2[a * 64];
  int n3 = resize_taps(64, y, 256, wv, &y0);
  const float* tp3 = t3 + (size_t)c * 16384 + y0 * 64 + x;
  float x3r = 0.f;
  for (int a = 0; a < n3; ++a) x3r += wv[a] * tp3[a * 64];
  float av = a0[i];
  float l = gelu_f(x1r);
  float m = gelu_f(av - l);
  float h = gelu_f(x2r - av);
  float sv = gelu_f(x3r - x2r);
  out[i] = l;
  out[65536 + i] = m;
  out[131072 + i] = h;
  out[196608 + i] = sv;
}

static inline int cdiv(int a, int b) { return (a + b - 1) / b; }

extern "C" void kernel_launch(void* const* d_in, const int* in_sizes, int n_in,
                              void* d_out, int out_size, void* d_ws, size_t ws_size,
                              hipStream_t stream) {
  (void)in_sizes; (void)n_in; (void)out_size; (void)ws_size;
  const float* x = (const float*)d_in[0];
  const float* w_off[4] = {(const float*)d_in[1], (const float*)d_in[5],
                           (const float*)d_in[9], (const float*)d_in[13]};
  const float* b_off[4] = {(const float*)d_in[2], (const float*)d_in[6],
                           (const float*)d_in[10], (const float*)d_in[14]};
  const float* w_c[4] = {(const float*)d_in[3], (const float*)d_in[7],
                         (const float*)d_in[11], (const float*)d_in[15]};
  const float* b_c[4] = {(const float*)d_in[4], (const float*)d_in[8],
                         (const float*)d_in[12], (const float*)d_in[16]};
  float* out = (float*)d_out;

  // Workspace (floats), lifetime-aliased; peak 7,166,464 f = 28.7 MB.
  float* ws = (float*)d_ws;
  float* a0 = ws;                  // [0, 65536)
  float* a1 = ws + 65536;          // [65536, 81920)
  float* a2 = ws + 81920;          // [81920, 344064)
  float* wT = ws + 344064;         // [344064, 422400)
  float* x1s = ws + 422400;        // [422400, 487936)   dead after k_fused
  float* t3 = ws + 422400;         // ALIAS x1s+ (written post-fused)
  float* t2 = ws + 684544;         // [684544, 815616)
  float* x2s = ws + 875008;        // [875008, 1923584)
  float* x3s = ws + 1923584;       // [1923584, 6117888)
  float* a3 = ws + 6117888;        // [6117888, 7166464)
  float* wTd = wT;                 // 4 x 9216
  float* wTc = wT + 36864;         // 4 x 10368

  FArgs fa;
  const float* ins[4] = {x1s, x, x2s, x3s};
  float* as[4] = {a1, a0, a2, a3};
  for (int s = 0; s < 4; ++s) {
    fa.in[s] = ins[s];
    fa.wc[s] = wTc + s * 10368;
    fa.bc[s] = b_off[s];
    fa.wd[s] = wTd + (3 - s) * 9216;
    fa.bd[s] = b_c[3 - s];
    fa.out[s] = as[s];
  }

  k_front<<<cdiv(1192448, BDIM), BDIM, 0, stream>>>(
      x, x1s, x2s, w_c[0], w_c[1], w_c[2], w_c[3],
      w_off[0], w_off[1], w_off[2], w_off[3], wT);
  k_up3<<<cdiv(64 * 256 * 256, BDIM), BDIM, 0, stream>>>(x2s, x3s);
  k_fused<<<1360, 512, 0, stream>>>(fa);
  k_hpass<<<cdiv(262144 + 131072, BDIM), BDIM, 0, stream>>>(a2, a3, t2, t3);
  k_final2<<<cdiv(65536, BDIM), BDIM, 0, stream>>>(a0, a1, t2, t3, out);
}

// Round 15
// 198.402 us; speedup vs baseline: 3.8527x; 1.1154x over previous
//
#include <hip/hip_runtime.h>
#include <math.h>

#define BDIM 256

typedef float v2f __attribute__((ext_vector_type(2)));

__device__ __forceinline__ v2f pkfma(v2f a, v2f b, v2f c) {
#if __has_builtin(__builtin_elementwise_fma)
  return __builtin_elementwise_fma(a, b, c);
#else
  v2f d;
  d.x = fmaf(a.x, b.x, c.x);
  d.y = fmaf(a.y, b.y, c.y);
  return d;
#endif
}

// ---------------------------------------------------------------------------
// jax.image.resize (bilinear/triangle, antialias=True) tap weights.
// ---------------------------------------------------------------------------
__device__ __forceinline__ int resize_taps(int out_n, int o, int in_n,
                                           float* w, int* i0) {
  float inv_scale = (float)in_n / (float)out_n;
  float ks = inv_scale > 1.f ? inv_scale : 1.f;
  float sf = ((float)o + 0.5f) * inv_scale - 0.5f;
  int lo = (int)ceilf(sf - ks);
  int hi = (int)floorf(sf + ks);
  if (lo < 0) lo = 0;
  if (hi > in_n - 1) hi = in_n - 1;
  int n = hi - lo + 1;
  float sum = 0.f;
  for (int k = 0; k < n; ++k) {
    float t = 1.f - fabsf((float)(lo + k) - sf) / ks;
    t = t > 0.f ? t : 0.f;
    w[k] = t;
    sum += t;
  }
  float inv = 1.f / sum;
  for (int k = 0; k < n; ++k) w[k] *= inv;
  *i0 = lo;
  return n;
}

__device__ __forceinline__ float resize_one(const float* __restrict__ plane,
                                            int Hi, int Wi, int oy, int ox,
                                            int Ho, int Wo) {
  float wy[8], wx[8];
  int y0, x0;
  int ny = resize_taps(Ho, oy, Hi, wy, &y0);
  int nx = resize_taps(Wo, ox, Wi, wx, &x0);
  float acc = 0.f;
  for (int a = 0; a < ny; ++a) {
    const float* row = plane + (y0 + a) * Wi + x0;
    float r = 0.f;
    for (int b = 0; b < nx; ++b) r += wx[b] * row[b];
    acc += wy[a] * r;
  }
  return acc;
}

// Hardcoded jax 2x bilinear upsample taps (antialias irrelevant, scale>1):
// o even=2m: taps (m-1,m) w (.25,.75); o odd=2m+1: taps (m,m+1) w (.75,.25);
// edges o=0 / o=2n-1: single tap weight 1 (clamp + renorm).
__device__ __forceinline__ void up2(int o, int n, int* t, float* w) {
  int m = o >> 1;
  if (o == 0) { t[0] = 0; w[0] = 1.f; t[1] = 0; w[1] = 0.f; }
  else if (o == 2 * n - 1) { t[0] = n - 1; w[0] = 1.f; t[1] = n - 1; w[1] = 0.f; }
  else if (o & 1) { t[0] = m; w[0] = 0.75f; t[1] = m + 1; w[1] = 0.25f; }
  else { t[0] = m - 1; w[0] = 0.25f; t[1] = m; w[1] = 0.75f; }
}

// ---------------------------------------------------------------------------
// FRONT: x1s (64->32), x2s (64->128), x3s (64->256 via composed 2x·2x
// hardcoded taps, reads only x), weight transpose. ONE launch.
// ---------------------------------------------------------------------------
__global__ void k_front(const float* __restrict__ x, float* __restrict__ x1s,
                        float* __restrict__ x2s, float* __restrict__ x3s,
                        const float* __restrict__ d0, const float* __restrict__ d1,
                        const float* __restrict__ d2, const float* __restrict__ d3,
                        const float* __restrict__ c0, const float* __restrict__ c1,
                        const float* __restrict__ c2, const float* __restrict__ c3,
                        float* __restrict__ wT) {
  int idx = blockIdx.x * BDIM + threadIdx.x;
  if (idx < 65536) {
    int ox = idx & 31, oy = (idx >> 5) & 31, c = idx >> 10;
    x1s[idx] = resize_one(x + c * 4096, 64, 64, oy, ox, 32, 32);
  } else if (idx < 1114112) {
    int j = idx - 65536;
    int ox = j & 127, oy = (j >> 7) & 127, c = j >> 14;
    x2s[j] = resize_one(x + c * 4096, 64, 64, oy, ox, 128, 128);
  } else if (idx < 5308416) {
    int j = idx - 1114112;
    int ox = j & 255, oy = (j >> 8) & 255, c = j >> 16;
    // composed 256<-128<-64: 4 (row,w) and 4 (col,w) pairs in x space
    int ty[2], tx[2];
    float twy[2], twx[2];
    up2(oy, 128, ty, twy);
    up2(ox, 128, tx, twx);
    int ry[4], rx[4];
    float rwy[4], rwx[4];
#pragma unroll
    for (int a = 0; a < 2; ++a) {
      int t2[2];
      float w2[2];
      up2(ty[a], 64, t2, w2);
      ry[2 * a] = t2[0]; rwy[2 * a] = twy[a] * w2[0];
      ry[2 * a + 1] = t2[1]; rwy[2 * a + 1] = twy[a] * w2[1];
      up2(tx[a], 64, t2, w2);
      rx[2 * a] = t2[0]; rwx[2 * a] = twx[a] * w2[0];
      rx[2 * a + 1] = t2[1]; rwx[2 * a + 1] = twx[a] * w2[1];
    }
    const float* xc = x + c * 4096;
    float acc = 0.f;
#pragma unroll
    for (int a = 0; a < 4; ++a) {
      const float* row = xc + ry[a] * 64;
      float r = 0.f;
#pragma unroll
      for (int b = 0; b < 4; ++b) r += rwx[b] * row[rx[b]];
      acc += rwy[a] * r;
    }
    x3s[j] = acc;
  } else if (idx < 5386752) {
    int w = idx - 5308416;
    if (w < 36864) {
      int i = w / 9216, r = w % 9216;
      int o = r % 16, t = r / 16, c = t % 64, k = t / 64;
      const float* s = i == 0 ? d0 : i == 1 ? d1 : i == 2 ? d2 : d3;
      wT[w] = s[(o * 64 + c) * 9 + k];
    } else {
      int j = w - 36864;
      int i = j / 10368, r = j % 10368;
      int o = r % 18, t = r / 18, c = t % 64, k = t / 64;
      const float* s = i == 0 ? c0 : i == 1 ? c1 : i == 2 ? c2 : c3;
      wT[w] = s[(o * 64 + c) * 9 + k];
    }
  }
}

// ---------------------------------------------------------------------------
// FUSED offset-conv + deformable conv + leaky, all 4 scales in one grid.
// Segments big->small; per-segment bijective XCD swizzle (bl&7)*(n/8)+(bl>>3).
// Block = 512 thr = 8 waves; wave g owns channels [8g,8g+8) for 64 px (lane).
// v2f packed FMA; EXPLICIT load batches (va[8] / v00..v11[8]) force 8-32
// gathers in flight per iteration (compiler settled at VGPR=48 = no MLP).
// launch_bounds(512,4): 128-VGPR budget.
// ---------------------------------------------------------------------------
struct FArgs {
  const float* in[4];
  const float* wc[4];   // conv weights [k][c][o18]
  const float* bc[4];   // conv bias
  const float* wd[4];   // deform weights [k][c][o16] (crossed)
  const float* bd[4];   // deform bias (crossed)
  float* out[4];        // a1, a0, a2, a3
};

__global__ __launch_bounds__(512, 4) void k_fused(FArgs A) {
  __shared__ float red[8 * 64 * 18];   // 36 KB, stride 18 (2-way = free)
  int b = blockIdx.x;
  int s, b0, nseg;
  if (b < 1024)      { s = 3; b0 = 0;    nseg = 1024; }
  else if (b < 1280) { s = 2; b0 = 1024; nseg = 256; }
  else if (b < 1344) { s = 1; b0 = 1280; nseg = 64; }
  else               { s = 0; b0 = 1344; nseg = 16; }
  int bl = b - b0;
  int swz = (bl & 7) * (nseg >> 3) + (bl >> 3);
  int H = 32 << s, W = H, lw = 5 + s, HW = H * W;
  int pad = 4 - s, dil = pad;
  const float* in = A.in[s];
  int tid = threadIdx.x, lane = tid & 63;
  int gv = tid >> 6;
  int g = __builtin_amdgcn_readfirstlane(gv);
  int p = swz * 64 + lane;
  int py = p >> lw, px = p & (W - 1);
  const float* ipg = in + (size_t)(g * 8) * HW;
  float* myred = &red[(size_t)(gv * 64 + lane) * 18];
  const float* lred = &red[lane * 18];

  // ---------------- phase A: offset conv (18 ch), partial over 8 channels
  {
    v2f accA[9];
#pragma unroll
    for (int j = 0; j < 9; ++j) accA[j] = (v2f){0.f, 0.f};
    const float* wT = A.wc[s];
#pragma unroll
    for (int ky = 0; ky < 3; ++ky) {
#pragma unroll
      for (int kx = 0; kx < 3; ++kx) {
        int k = ky * 3 + kx;
        int yy = py + ky - 1, xx = px + kx - 1;
        float msk = (yy >= 0 && yy < H && xx >= 0 && xx < W) ? 1.f : 0.f;
        int ai = min(max(yy, 0), H - 1) * W + min(max(xx, 0), W - 1);
        // batch-load all 8 channels first (8 loads in flight)
        float va[8];
        {
          const float* ip = ipg + ai;
#pragma unroll
          for (int c = 0; c < 8; ++c, ip += HW) va[c] = *ip;
        }
        const v2f* wk2 = (const v2f*)(wT + (size_t)(k * 64 + g * 8) * 18);
#pragma unroll
        for (int c = 0; c < 8; ++c, wk2 += 9) {
          float v = va[c] * msk;
          v2f vv = {v, v};
#pragma unroll
          for (int j = 0; j < 9; ++j) accA[j] = pkfma(wk2[j], vv, accA[j]);
        }
      }
    }
#pragma unroll
    for (int j = 0; j < 9; ++j) *(v2f*)(myred + 2 * j) = accA[j];
  }
  __syncthreads();
  v2f off2[9];
  {
    const v2f* bc2 = (const v2f*)A.bc[s];
#pragma unroll
    for (int j = 0; j < 9; ++j) {
      v2f v = bc2[j];
#pragma unroll
      for (int r = 0; r < 8; ++r) v += *(const v2f*)(lred + (size_t)r * 64 * 18 + 2 * j);
      off2[j] = v;
    }
  }
  __syncthreads();   // all reads of red done before phase-B overwrites

  // ---------------- phase B: deformable conv (16 ch) using off2
  v2f acc2[8];
#pragma unroll
  for (int j = 0; j < 8; ++j) acc2[j] = (v2f){0.f, 0.f};
  {
    const float* wT = A.wd[s];
#pragma unroll
    for (int ky = 0; ky < 3; ++ky) {
#pragma unroll
      for (int kx = 0; kx < 3; ++kx) {
        int k = ky * 3 + kx;
        float dy = off2[k].x;
        float dx = off2[k].y;
        float pyf = (float)(py - pad + ky * dil) + dy;
        float pxf = (float)(px - pad + kx * dil) + dx;
        float fy0 = floorf(pyf), fx0 = floorf(pxf);
        float wy = pyf - fy0, wxv = pxf - fx0;
        int y0 = (int)fy0, x0 = (int)fx0;
        float xg = (x0 >= -1 && x0 <= W - 1) ? 1.f : 0.f;
        float r0 = (1.f - wy) * ((y0 >= 0 && y0 < H) ? xg : 0.f);
        float r1 = wy * ((y0 + 1 >= 0 && y0 + 1 < H) ? xg : 0.f);
        float cl = 1.f - wxv, cr = wxv;
        bool xlo = x0 < 0, xhi = x0 > W - 2;
        float W00 = xlo ? r0 * cr : (xhi ? 0.f : r0 * cl);
        float W01 = xlo ? 0.f : (xhi ? r0 * cl : r0 * cr);
        float W10 = xlo ? r1 * cr : (xhi ? 0.f : r1 * cl);
        float W11 = xlo ? 0.f : (xhi ? r1 * cl : r1 * cr);
        int ax = min(max(x0, 0), W - 2);
        int cy0 = min(max(y0, 0), H - 1);
        int cy1 = min(max(y0 + 1, 0), H - 1);
        int A0 = cy0 * W + ax, A1 = cy1 * W + ax;
        // batch-load all 32 corner values first (32 loads in flight)
        float v00[8], v01[8], v10[8], v11[8];
        {
          const float* ip = ipg;
#pragma unroll
          for (int c = 0; c < 8; ++c, ip += HW) {
            v00[c] = ip[A0];
            v01[c] = ip[A0 + 1];
            v10[c] = ip[A1];
            v11[c] = ip[A1 + 1];
          }
        }
        const v2f* wk2 = (const v2f*)(wT + (size_t)(k * 64 + g * 8) * 16);
#pragma unroll
        for (int c = 0; c < 8; ++c, wk2 += 8) {
          float sv = W00 * v00[c] + W01 * v01[c] + W10 * v10[c] + W11 * v11[c];
          v2f vv = {sv, sv};
#pragma unroll
          for (int j = 0; j < 8; ++j) acc2[j] = pkfma(wk2[j], vv, acc2[j]);
        }
      }
    }
  }
  if (gv) {
    float* wr = &red[(size_t)((gv - 1) * 64 + lane) * 18];
#pragma unroll
    for (int j = 0; j < 8; ++j) *(v2f*)(wr + 2 * j) = acc2[j];
  }
  __syncthreads();
  if (!gv) {
    const v2f* bd2 = (const v2f*)A.bd[s];
    float* out = A.out[s];
#pragma unroll
    for (int j = 0; j < 8; ++j) {
      v2f v = acc2[j] + bd2[j];
#pragma unroll
      for (int r = 0; r < 7; ++r) v += *(const v2f*)(lred + (size_t)r * 64 * 18 + 2 * j);
      float vx = v.x, vy = v.y;
      vx = vx >= 0.f ? vx : 0.01f * vx;
      vy = vy >= 0.f ? vy : 0.01f * vy;
      out[(size_t)(2 * j) * HW + p] = vx;
      out[(size_t)(2 * j + 1) * HW + p] = vy;
    }
  }
}

// ---------------------------------------------------------------------------
// Horizontal downsample pass: a3 (16,256,256) -> t3 (16,256,64) 8 taps;
// a2 (16,128,128) -> t2 (16,128,64) 4 taps.
// ---------------------------------------------------------------------------
__global__ void k_hpass(const float* __restrict__ a2, const float* __restrict__ a3,
                        float* __restrict__ t2, float* __restrict__ t3) {
  int idx = blockIdx.x * BDIM + threadIdx.x;
  if (idx < 262144) {
    int ox = idx & 63, y = (idx >> 6) & 255, c = idx >> 14;
    float wx[8];
    int x0;
    int n = resize_taps(64, ox, 256, wx, &x0);
    const float* row = a3 + (size_t)c * 65536 + y * 256 + x0;
    float r = 0.f;
    for (int b = 0; b < n; ++b) r += wx[b] * row[b];
    t3[idx] = r;
  } else {
    int j = idx - 262144;
    if (j < 131072) {
      int ox = j & 63, y = (j >> 6) & 127, c = j >> 13;
      float wx[8];
      int x0;
      int n = resize_taps(64, ox, 128, wx, &x0);
      const float* row = a2 + (size_t)c * 16384 + y * 128 + x0;
      float r = 0.f;
      for (int b = 0; b < n; ++b) r += wx[b] * row[b];
      t2[j] = r;
    }
  }
}

__device__ __forceinline__ float gelu_f(float x) {
  return 0.5f * x * (1.f + erff(x * 0.70710678118654752f));
}

// Vertical taps + gelu combine.
__global__ void k_final2(const float* __restrict__ a0, const float* __restrict__ a1,
                         const float* __restrict__ t2, const float* __restrict__ t3,
                         float* __restrict__ out) {
  int i = blockIdx.x * BDIM + threadIdx.x;  // [0, 65536)
  int x = i & 63, y = (i >> 6) & 63, c = i >> 12;
  float x1r = resize_one(a1 + c * 1024, 32, 32, y, x, 64, 64);
  float wv[8];
  int y0;
  int n2 = resize_taps(64, y, 128, wv, &y0);
  const float* tp2 = t2 + (size_t)c * 8192 + y0 * 64 + x;
  float x2r = 0.f;
  for (int a = 0; a < n2; ++a) x2r += wv[a] * tp2[a * 64];
  int n3 = resize_taps(64, y, 256, wv, &y0);
  const float* tp3 = t3 + (size_t)c * 16384 + y0 * 64 + x;
  float x3r = 0.f;
  for (int a = 0; a < n3; ++a) x3r += wv[a] * tp3[a * 64];
  float av = a0[i];
  float l = gelu_f(x1r);
  float m = gelu_f(av - l);
  float h = gelu_f(x2r - av);
  float sv = gelu_f(x3r - x2r);
  out[i] = l;
  out[65536 + i] = m;
  out[131072 + i] = h;
  out[196608 + i] = sv;
}

static inline int cdiv(int a, int b) { return (a + b - 1) / b; }

extern "C" void kernel_launch(void* const* d_in, const int* in_sizes, int n_in,
                              void* d_out, int out_size, void* d_ws, size_t ws_size,
                              hipStream_t stream) {
  (void)in_sizes; (void)n_in; (void)out_size; (void)ws_size;
  const float* x = (const float*)d_in[0];
  const float* w_off[4] = {(const float*)d_in[1], (const float*)d_in[5],
                           (const float*)d_in[9], (const float*)d_in[13]};
  const float* b_off[4] = {(const float*)d_in[2], (const float*)d_in[6],
                           (const float*)d_in[10], (const float*)d_in[14]};
  const float* w_c[4] = {(const float*)d_in[3], (const float*)d_in[7],
                         (const float*)d_in[11], (const float*)d_in[15]};
  const float* b_c[4] = {(const float*)d_in[4], (const float*)d_in[8],
                         (const float*)d_in[12], (const float*)d_in[16]};
  float* out = (float*)d_out;

  // Workspace (floats), lifetime-aliased; peak 7,166,464 f = 28.7 MB.
  float* ws = (float*)d_ws;
  float* a0 = ws;                  // [0, 65536)
  float* a1 = ws + 65536;          // [65536, 81920)
  float* a2 = ws + 81920;          // [81920, 344064)
  float* wT = ws + 344064;         // [344064, 422400)
  float* x1s = ws + 422400;        // [422400, 487936)   dead after k_fused
  float* t3 = ws + 422400;         // ALIAS x1s+ (written post-fused)
  float* t2 = ws + 684544;         // [684544, 815616)
  float* x2s = ws + 875008;        // [875008, 1923584)
  float* x3s = ws + 1923584;       // [1923584, 6117888)
  float* a3 = ws + 6117888;        // [6117888, 7166464)
  float* wTd = wT;                 // 4 x 9216
  float* wTc = wT + 36864;         // 4 x 10368

  FArgs fa;
  const float* ins[4] = {x1s, x, x2s, x3s};
  float* as[4] = {a1, a0, a2, a3};
  for (int s = 0; s < 4; ++s) {
    fa.in[s] = ins[s];
    fa.wc[s] = wTc + s * 10368;
    fa.bc[s] = b_off[s];
    fa.wd[s] = wTd + (3 - s) * 9216;
    fa.bd[s] = b_c[3 - s];
    fa.out[s] = as[s];
  }

  k_front<<<cdiv(5386752, BDIM), BDIM, 0, stream>>>(
      x, x1s, x2s, x3s, w_c[0], w_c[1], w_c[2], w_c[3],
      w_off[0], w_off[1], w_off[2], w_off[3], wT);
  k_fused<<<1360, 512, 0, stream>>>(fa);
  k_hpass<<<cdiv(262144 + 131072, BDIM), BDIM, 0, stream>>>(a2, a3, t2, t3);
  k_final2<<<cdiv(65536, BDIM), BDIM, 0, stream>>>(a0, a1, t2, t3, out);
}

// Round 16
// 180.115 us; speedup vs baseline: 4.2438x; 1.1015x over previous
//
#include <hip/hip_runtime.h>
#include <math.h>

#define BDIM 256

typedef float v2f __attribute__((ext_vector_type(2)));

__device__ __forceinline__ v2f pkfma(v2f a, v2f b, v2f c) {
#if __has_builtin(__builtin_elementwise_fma)
  return __builtin_elementwise_fma(a, b, c);
#else
  v2f d;
  d.x = fmaf(a.x, b.x, c.x);
  d.y = fmaf(a.y, b.y, c.y);
  return d;
#endif
}

// ---------------------------------------------------------------------------
// jax.image.resize (bilinear/triangle, antialias=True) tap weights.
// ---------------------------------------------------------------------------
__device__ __forceinline__ int resize_taps(int out_n, int o, int in_n,
                                           float* w, int* i0) {
  float inv_scale = (float)in_n / (float)out_n;
  float ks = inv_scale > 1.f ? inv_scale : 1.f;
  float sf = ((float)o + 0.5f) * inv_scale - 0.5f;
  int lo = (int)ceilf(sf - ks);
  int hi = (int)floorf(sf + ks);
  if (lo < 0) lo = 0;
  if (hi > in_n - 1) hi = in_n - 1;
  int n = hi - lo + 1;
  float sum = 0.f;
  for (int k = 0; k < n; ++k) {
    float t = 1.f - fabsf((float)(lo + k) - sf) / ks;
    t = t > 0.f ? t : 0.f;
    w[k] = t;
    sum += t;
  }
  float inv = 1.f / sum;
  for (int k = 0; k < n; ++k) w[k] *= inv;
  *i0 = lo;
  return n;
}

__device__ __forceinline__ float resize_one(const float* __restrict__ plane,
                                            int Hi, int Wi, int oy, int ox,
                                            int Ho, int Wo) {
  float wy[8], wx[8];
  int y0, x0;
  int ny = resize_taps(Ho, oy, Hi, wy, &y0);
  int nx = resize_taps(Wo, ox, Wi, wx, &x0);
  float acc = 0.f;
  for (int a = 0; a < ny; ++a) {
    const float* row = plane + (y0 + a) * Wi + x0;
    float r = 0.f;
    for (int b = 0; b < nx; ++b) r += wx[b] * row[b];
    acc += wy[a] * r;
  }
  return acc;
}

// Hardcoded jax 2x bilinear upsample taps (scale>1 => no antialias change):
// o even=2m: taps (m-1,m) w (.25,.75); o odd=2m+1: taps (m,m+1) w (.75,.25);
// edges o=0 / o=2n-1: single tap weight 1 (clamp + renorm).
__device__ __forceinline__ void up2(int o, int n, int* t, float* w) {
  int m = o >> 1;
  if (o == 0) { t[0] = 0; w[0] = 1.f; t[1] = 0; w[1] = 0.f; }
  else if (o == 2 * n - 1) { t[0] = n - 1; w[0] = 1.f; t[1] = n - 1; w[1] = 0.f; }
  else if (o & 1) { t[0] = m; w[0] = 0.75f; t[1] = m + 1; w[1] = 0.25f; }
  else { t[0] = m - 1; w[0] = 0.25f; t[1] = m; w[1] = 0.75f; }
}

// pair-layout store: channel c, pixel pix, plane size HW (floats)
__device__ __forceinline__ void pstore(float* __restrict__ dst, int c, int pix,
                                       int HW, float v) {
  dst[((size_t)(c >> 1) * HW + pix) * 2 + (c & 1)] = v;
}

// ---------------------------------------------------------------------------
// FRONT: builds PAIRED-CHANNEL [c/2][HW][2] copies of all conv inputs:
//   x1p (32->), x2p, x3p (composed 2x·2x from x), xp (copy of x), + wT.
// ---------------------------------------------------------------------------
__global__ void k_front(const float* __restrict__ x, float* __restrict__ x1p,
                        float* __restrict__ x2p, float* __restrict__ x3p,
                        float* __restrict__ xp,
                        const float* __restrict__ d0, const float* __restrict__ d1,
                        const float* __restrict__ d2, const float* __restrict__ d3,
                        const float* __restrict__ c0, const float* __restrict__ c1,
                        const float* __restrict__ c2, const float* __restrict__ c3,
                        float* __restrict__ wT) {
  int idx = blockIdx.x * BDIM + threadIdx.x;
  if (idx < 65536) {
    int ox = idx & 31, oy = (idx >> 5) & 31, c = idx >> 10;
    pstore(x1p, c, oy * 32 + ox, 1024,
           resize_one(x + c * 4096, 64, 64, oy, ox, 32, 32));
  } else if (idx < 1114112) {
    int j = idx - 65536;
    int ox = j & 127, oy = (j >> 7) & 127, c = j >> 14;
    pstore(x2p, c, oy * 128 + ox, 16384,
           resize_one(x + c * 4096, 64, 64, oy, ox, 128, 128));
  } else if (idx < 5308416) {
    int j = idx - 1114112;
    int ox = j & 255, oy = (j >> 8) & 255, c = j >> 16;
    int ty[2], tx[2];
    float twy[2], twx[2];
    up2(oy, 128, ty, twy);
    up2(ox, 128, tx, twx);
    int ry[4], rx[4];
    float rwy[4], rwx[4];
#pragma unroll
    for (int a = 0; a < 2; ++a) {
      int t2[2];
      float w2[2];
      up2(ty[a], 64, t2, w2);
      ry[2 * a] = t2[0]; rwy[2 * a] = twy[a] * w2[0];
      ry[2 * a + 1] = t2[1]; rwy[2 * a + 1] = twy[a] * w2[1];
      up2(tx[a], 64, t2, w2);
      rx[2 * a] = t2[0]; rwx[2 * a] = twx[a] * w2[0];
      rx[2 * a + 1] = t2[1]; rwx[2 * a + 1] = twx[a] * w2[1];
    }
    const float* xc = x + c * 4096;
    float acc = 0.f;
#pragma unroll
    for (int a = 0; a < 4; ++a) {
      const float* row = xc + ry[a] * 64;
      float r = 0.f;
#pragma unroll
      for (int b = 0; b < 4; ++b) r += rwx[b] * row[rx[b]];
      acc += rwy[a] * r;
    }
    pstore(x3p, c, oy * 256 + ox, 65536, acc);
  } else if (idx < 5386752) {
    int w = idx - 5308416;
    if (w < 36864) {
      int i = w / 9216, r = w % 9216;
      int o = r % 16, t = r / 16, c = t % 64, k = t / 64;
      const float* s = i == 0 ? d0 : i == 1 ? d1 : i == 2 ? d2 : d3;
      wT[w] = s[(o * 64 + c) * 9 + k];
    } else {
      int j = w - 36864;
      int i = j / 10368, r = j % 10368;
      int o = r % 18, t = r / 18, c = t % 64, k = t / 64;
      const float* s = i == 0 ? c0 : i == 1 ? c1 : i == 2 ? c2 : c3;
      wT[w] = s[(o * 64 + c) * 9 + k];
    }
  } else if (idx < 5648896) {
    int j = idx - 5386752;        // copy x -> paired xp
    int c = j >> 12, pix = j & 4095;
    pstore(xp, c, pix, 4096, x[j]);
  }
}

// ---------------------------------------------------------------------------
// FUSED offset-conv + deformable conv + leaky, all 4 scales in one grid.
// Inputs in PAIRED-CHANNEL layout: one v2f load = 2 channels at a pixel
// (halves gather instruction count AND cache-line transactions).
// Segments big->small; per-segment bijective XCD swizzle (bl&7)*(n/8)+(bl>>3).
// Block = 512 thr = 8 waves; wave g owns channel-pairs [4g,4g+4) (=8 ch).
// launch_bounds(512,4): 128-VGPR budget.
// ---------------------------------------------------------------------------
struct FArgs {
  const float* in[4];   // paired-channel images
  const float* wc[4];   // conv weights [k][c][o18]
  const float* bc[4];   // conv bias
  const float* wd[4];   // deform weights [k][c][o16] (crossed)
  const float* bd[4];   // deform bias (crossed)
  float* out[4];        // a1, a0, a2, a3 (scalar CHW)
};

__global__ __launch_bounds__(512, 4) void k_fused(FArgs A) {
  __shared__ float red[8 * 64 * 18];   // 36 KB, stride 18 (2-way = free)
  int b = blockIdx.x;
  int s, b0, nseg;
  if (b < 1024)      { s = 3; b0 = 0;    nseg = 1024; }
  else if (b < 1280) { s = 2; b0 = 1024; nseg = 256; }
  else if (b < 1344) { s = 1; b0 = 1280; nseg = 64; }
  else               { s = 0; b0 = 1344; nseg = 16; }
  int bl = b - b0;
  int swz = (bl & 7) * (nseg >> 3) + (bl >> 3);
  int H = 32 << s, W = H, lw = 5 + s, HW = H * W;
  int pad = 4 - s, dil = pad;
  int tid = threadIdx.x, lane = tid & 63;
  int gv = tid >> 6;
  int g = __builtin_amdgcn_readfirstlane(gv);
  int p = swz * 64 + lane;
  int py = p >> lw, px = p & (W - 1);
  const v2f* ipg2 = (const v2f*)A.in[s] + (size_t)(g * 4) * HW;
  float* myred = &red[(size_t)(gv * 64 + lane) * 18];
  const float* lred = &red[lane * 18];

  // ---------------- phase A: offset conv (18 ch), partial over 8 channels
  {
    v2f accA[9];
#pragma unroll
    for (int j = 0; j < 9; ++j) accA[j] = (v2f){0.f, 0.f};
    const float* wT = A.wc[s];
#pragma unroll
    for (int ky = 0; ky < 3; ++ky) {
#pragma unroll
      for (int kx = 0; kx < 3; ++kx) {
        int k = ky * 3 + kx;
        int yy = py + ky - 1, xx = px + kx - 1;
        float msk = (yy >= 0 && yy < H && xx >= 0 && xx < W) ? 1.f : 0.f;
        int ai = min(max(yy, 0), H - 1) * W + min(max(xx, 0), W - 1);
        v2f va[4];
#pragma unroll
        for (int cp = 0; cp < 4; ++cp) va[cp] = ipg2[(size_t)cp * HW + ai];
        const float* wkb = wT + (size_t)(k * 64 + g * 8) * 18;
#pragma unroll
        for (int cp = 0; cp < 4; ++cp) {
          float vx = va[cp].x * msk;
          float vy = va[cp].y * msk;
          const v2f* w0 = (const v2f*)(wkb + (2 * cp) * 18);
          const v2f* w1 = (const v2f*)(wkb + (2 * cp + 1) * 18);
          v2f vvx = {vx, vx}, vvy = {vy, vy};
#pragma unroll
          for (int j = 0; j < 9; ++j) accA[j] = pkfma(w0[j], vvx, accA[j]);
#pragma unroll
          for (int j = 0; j < 9; ++j) accA[j] = pkfma(w1[j], vvy, accA[j]);
        }
      }
    }
#pragma unroll
    for (int j = 0; j < 9; ++j) *(v2f*)(myred + 2 * j) = accA[j];
  }
  __syncthreads();
  v2f off2[9];
  {
    const v2f* bc2 = (const v2f*)A.bc[s];
#pragma unroll
    for (int j = 0; j < 9; ++j) {
      v2f v = bc2[j];
#pragma unroll
      for (int r = 0; r < 8; ++r) v += *(const v2f*)(lred + (size_t)r * 64 * 18 + 2 * j);
      off2[j] = v;
    }
  }
  __syncthreads();   // all reads of red done before phase-B overwrites

  // ---------------- phase B: deformable conv (16 ch) using off2
  v2f acc2[8];
#pragma unroll
  for (int j = 0; j < 8; ++j) acc2[j] = (v2f){0.f, 0.f};
  {
    const float* wT = A.wd[s];
#pragma unroll
    for (int ky = 0; ky < 3; ++ky) {
#pragma unroll
      for (int kx = 0; kx < 3; ++kx) {
        int k = ky * 3 + kx;
        float dy = off2[k].x;
        float dx = off2[k].y;
        float pyf = (float)(py - pad + ky * dil) + dy;
        float pxf = (float)(px - pad + kx * dil) + dx;
        float fy0 = floorf(pyf), fx0 = floorf(pxf);
        float wy = pyf - fy0, wxv = pxf - fx0;
        int y0 = (int)fy0, x0 = (int)fx0;
        float xg = (x0 >= -1 && x0 <= W - 1) ? 1.f : 0.f;
        float r0 = (1.f - wy) * ((y0 >= 0 && y0 < H) ? xg : 0.f);
        float r1 = wy * ((y0 + 1 >= 0 && y0 + 1 < H) ? xg : 0.f);
        float cl = 1.f - wxv, cr = wxv;
        bool xlo = x0 < 0, xhi = x0 > W - 2;
        float W00 = xlo ? r0 * cr : (xhi ? 0.f : r0 * cl);
        float W01 = xlo ? 0.f : (xhi ? r0 * cl : r0 * cr);
        float W10 = xlo ? r1 * cr : (xhi ? 0.f : r1 * cl);
        float W11 = xlo ? 0.f : (xhi ? r1 * cl : r1 * cr);
        int ax = min(max(x0, 0), W - 2);
        int cy0 = min(max(y0, 0), H - 1);
        int cy1 = min(max(y0 + 1, 0), H - 1);
        int A0 = cy0 * W + ax, A1 = cy1 * W + ax;
        v2f W00v = {W00, W00}, W01v = {W01, W01};
        v2f W10v = {W10, W10}, W11v = {W11, W11};
        // 4 paired loads per channel-pair: 16 loads for 8 channels
        v2f q00[4], q01[4], q10[4], q11[4];
#pragma unroll
        for (int cp = 0; cp < 4; ++cp) {
          const v2f* ipp = ipg2 + (size_t)cp * HW;
          q00[cp] = ipp[A0];
          q01[cp] = ipp[A0 + 1];
          q10[cp] = ipp[A1];
          q11[cp] = ipp[A1 + 1];
        }
        const float* wkb = wT + (size_t)(k * 64 + g * 8) * 16;
#pragma unroll
        for (int cp = 0; cp < 4; ++cp) {
          v2f sv2 = q00[cp] * W00v;
          sv2 = pkfma(q01[cp], W01v, sv2);
          sv2 = pkfma(q10[cp], W10v, sv2);
          sv2 = pkfma(q11[cp], W11v, sv2);
          const v2f* w0 = (const v2f*)(wkb + (2 * cp) * 16);
          const v2f* w1 = (const v2f*)(wkb + (2 * cp + 1) * 16);
          v2f vvx = {sv2.x, sv2.x}, vvy = {sv2.y, sv2.y};
#pragma unroll
          for (int j = 0; j < 8; ++j) acc2[j] = pkfma(w0[j], vvx, acc2[j]);
#pragma unroll
          for (int j = 0; j < 8; ++j) acc2[j] = pkfma(w1[j], vvy, acc2[j]);
        }
      }
    }
  }
  if (gv) {
    float* wr = &red[(size_t)((gv - 1) * 64 + lane) * 18];
#pragma unroll
    for (int j = 0; j < 8; ++j) *(v2f*)(wr + 2 * j) = acc2[j];
  }
  __syncthreads();
  if (!gv) {
    const v2f* bd2 = (const v2f*)A.bd[s];
    float* out = A.out[s];
#pragma unroll
    for (int j = 0; j < 8; ++j) {
      v2f v = acc2[j] + bd2[j];
#pragma unroll
      for (int r = 0; r < 7; ++r) v += *(const v2f*)(lred + (size_t)r * 64 * 18 + 2 * j);
      float vx = v.x, vy = v.y;
      vx = vx >= 0.f ? vx : 0.01f * vx;
      vy = vy >= 0.f ? vy : 0.01f * vy;
      out[(size_t)(2 * j) * HW + p] = vx;
      out[(size_t)(2 * j + 1) * HW + p] = vy;
    }
  }
}

// ---------------------------------------------------------------------------
// Horizontal downsample pass: a3 (16,256,256) -> t3 (16,256,64) 8 taps;
// a2 (16,128,128) -> t2 (16,128,64) 4 taps.
// ---------------------------------------------------------------------------
__global__ void k_hpass(const float* __restrict__ a2, const float* __restrict__ a3,
                        float* __restrict__ t2, float* __restrict__ t3) {
  int idx = blockIdx.x * BDIM + threadIdx.x;
  if (idx < 262144) {
    int ox = idx & 63, y = (idx >> 6) & 255, c = idx >> 14;
    float wx[8];
    int x0;
    int n = resize_taps(64, ox, 256, wx, &x0);
    const float* row = a3 + (size_t)c * 65536 + y * 256 + x0;
    float r = 0.f;
    for (int b = 0; b < n; ++b) r += wx[b] * row[b];
    t3[idx] = r;
  } else {
    int j = idx - 262144;
    if (j < 131072) {
      int ox = j & 63, y = (j >> 6) & 127, c = j >> 13;
      float wx[8];
      int x0;
      int n = resize_taps(64, ox, 128, wx, &x0);
      const float* row = a2 + (size_t)c * 16384 + y * 128 + x0;
      float r = 0.f;
      for (int b = 0; b < n; ++b) r += wx[b] * row[b];
      t2[j] = r;
    }
  }
}

__device__ __forceinline__ float gelu_f(float x) {
  return 0.5f * x * (1.f + erff(x * 0.70710678118654752f));
}

// Vertical taps + gelu combine.
__global__ void k_final2(const float* __restrict__ a0, const float* __restrict__ a1,
                         const float* __restrict__ t2, const float* __restrict__ t3,
                         float* __restrict__ out) {
  int i = blockIdx.x * BDIM + threadIdx.x;  // [0, 65536)
  int x = i & 63, y = (i >> 6) & 63, c = i >> 12;
  float x1r = resize_one(a1 + c * 1024, 32, 32, y, x, 64, 64);
  float wv[8];
  int y0;
  int n2 = resize_taps(64, y, 128, wv, &y0);
  const float* tp2 = t2 + (size_t)c * 8192 + y0 * 64 + x;
  float x2r = 0.f;
  for (int a = 0; a < n2; ++a) x2r += wv[a] * tp2[a * 64];
  int n3 = resize_taps(64, y, 256, wv, &y0);
  const float* tp3 = t3 + (size_t)c * 16384 + y0 * 64 + x;
  float x3r = 0.f;
  for (int a = 0; a < n3; ++a) x3r += wv[a] * tp3[a * 64];
  float av = a0[i];
  float l = gelu_f(x1r);
  float m = gelu_f(av - l);
  float h = gelu_f(x2r - av);
  float sv = gelu_f(x3r - x2r);
  out[i] = l;
  out[65536 + i] = m;
  out[131072 + i] = h;
  out[196608 + i] = sv;
}

static inline int cdiv(int a, int b) { return (a + b - 1) / b; }

extern "C" void kernel_launch(void* const* d_in, const int* in_sizes, int n_in,
                              void* d_out, int out_size, void* d_ws, size_t ws_size,
                              hipStream_t stream) {
  (void)in_sizes; (void)n_in; (void)out_size; (void)ws_size;
  const float* x = (const float*)d_in[0];
  const float* w_off[4] = {(const float*)d_in[1], (const float*)d_in[5],
                           (const float*)d_in[9], (const float*)d_in[13]};
  const float* b_off[4] = {(const float*)d_in[2], (const float*)d_in[6],
                           (const float*)d_in[10], (const float*)d_in[14]};
  const float* w_c[4] = {(const float*)d_in[3], (const float*)d_in[7],
                         (const float*)d_in[11], (const float*)d_in[15]};
  const float* b_c[4] = {(const float*)d_in[4], (const float*)d_in[8],
                         (const float*)d_in[12], (const float*)d_in[16]};
  float* out = (float*)d_out;

  // Workspace (floats), lifetime-aliased; peak 7,428,608 f = 29.7 MB
  // (ws_size >= 33.4 MB established in R8).
  float* ws = (float*)d_ws;
  float* a0 = ws;                  // [0, 65536)
  float* a1 = ws + 65536;          // [65536, 81920)
  float* a2 = ws + 81920;          // [81920, 344064)
  float* wT = ws + 344064;         // [344064, 422400)
  float* x1p = ws + 422400;        // [422400, 487936)   dead after k_fused
  float* t3 = ws + 422400;         // ALIAS x1p+ (written post-fused)
  float* t2 = ws + 684544;         // [684544, 815616)
  float* x2p = ws + 875008;        // [875008, 1923584)
  float* x3p = ws + 1923584;       // [1923584, 6117888)
  float* a3 = ws + 6117888;        // [6117888, 7166464)
  float* xp = ws + 7166464;        // [7166464, 7428608)
  float* wTd = wT;                 // 4 x 9216
  float* wTc = wT + 36864;         // 4 x 10368

  FArgs fa;
  const float* ins[4] = {x1p, xp, x2p, x3p};
  float* as[4] = {a1, a0, a2, a3};
  for (int s = 0; s < 4; ++s) {
    fa.in[s] = ins[s];
    fa.wc[s] = wTc + s * 10368;
    fa.bc[s] = b_off[s];
    fa.wd[s] = wTd + (3 - s) * 9216;
    fa.bd[s] = b_c[3 - s];
    fa.out[s] = as[s];
  }

  k_front<<<cdiv(5648896, BDIM), BDIM, 0, stream>>>(
      x, x1p, x2p, x3p, xp, w_c[0], w_c[1], w_c[2], w_c[3],
      w_off[0], w_off[1], w_off[2], w_off[3], wT);
  k_fused<<<1360, 512, 0, stream>>>(fa);
  k_hpass<<<cdiv(262144 + 131072, BDIM), BDIM, 0, stream>>>(a2, a3, t2, t3);
  k_final2<<<cdiv(65536, BDIM), BDIM, 0, stream>>>(a0, a1, t2, t3, out);
}

// Round 17
// 179.419 us; speedup vs baseline: 4.2603x; 1.0039x over previous
//
#include <hip/hip_runtime.h>
#include <math.h>

#define BDIM 256

typedef float v2f __attribute__((ext_vector_type(2)));
typedef float v4f __attribute__((ext_vector_type(4)));

__device__ __forceinline__ v2f pkfma(v2f a, v2f b, v2f c) {
#if __has_builtin(__builtin_elementwise_fma)
  return __builtin_elementwise_fma(a, b, c);
#else
  v2f d;
  d.x = fmaf(a.x, b.x, c.x);
  d.y = fmaf(a.y, b.y, c.y);
  return d;
#endif
}

__device__ __forceinline__ v4f pkfma4(v4f a, v4f b, v4f c) {
#if __has_builtin(__builtin_elementwise_fma)
  return __builtin_elementwise_fma(a, b, c);
#else
  v4f d;
  d.x = fmaf(a.x, b.x, c.x);
  d.y = fmaf(a.y, b.y, c.y);
  d.z = fmaf(a.z, b.z, c.z);
  d.w = fmaf(a.w, b.w, c.w);
  return d;
#endif
}

// ---------------------------------------------------------------------------
// jax.image.resize (bilinear/triangle, antialias=True) tap weights.
// ---------------------------------------------------------------------------
__device__ __forceinline__ int resize_taps(int out_n, int o, int in_n,
                                           float* w, int* i0) {
  float inv_scale = (float)in_n / (float)out_n;
  float ks = inv_scale > 1.f ? inv_scale : 1.f;
  float sf = ((float)o + 0.5f) * inv_scale - 0.5f;
  int lo = (int)ceilf(sf - ks);
  int hi = (int)floorf(sf + ks);
  if (lo < 0) lo = 0;
  if (hi > in_n - 1) hi = in_n - 1;
  int n = hi - lo + 1;
  float sum = 0.f;
  for (int k = 0; k < n; ++k) {
    float t = 1.f - fabsf((float)(lo + k) - sf) / ks;
    t = t > 0.f ? t : 0.f;
    w[k] = t;
    sum += t;
  }
  float inv = 1.f / sum;
  for (int k = 0; k < n; ++k) w[k] *= inv;
  *i0 = lo;
  return n;
}

__device__ __forceinline__ float resize_one(const float* __restrict__ plane,
                                            int Hi, int Wi, int oy, int ox,
                                            int Ho, int Wo) {
  float wy[8], wx[8];
  int y0, x0;
  int ny = resize_taps(Ho, oy, Hi, wy, &y0);
  int nx = resize_taps(Wo, ox, Wi, wx, &x0);
  float acc = 0.f;
  for (int a = 0; a < ny; ++a) {
    const float* row = plane + (y0 + a) * Wi + x0;
    float r = 0.f;
    for (int b = 0; b < nx; ++b) r += wx[b] * row[b];
    acc += wy[a] * r;
  }
  return acc;
}

// Hardcoded jax 2x bilinear upsample taps (scale>1 => no antialias change).
__device__ __forceinline__ void up2(int o, int n, int* t, float* w) {
  int m = o >> 1;
  if (o == 0) { t[0] = 0; w[0] = 1.f; t[1] = 0; w[1] = 0.f; }
  else if (o == 2 * n - 1) { t[0] = n - 1; w[0] = 1.f; t[1] = n - 1; w[1] = 0.f; }
  else if (o & 1) { t[0] = m; w[0] = 0.75f; t[1] = m + 1; w[1] = 0.25f; }
  else { t[0] = m - 1; w[0] = 0.25f; t[1] = m; w[1] = 0.75f; }
}

// quad-layout store: channel c, pixel pix, plane size HW (floats)
__device__ __forceinline__ void pstore4(float* __restrict__ dst, int c, int pix,
                                        int HW, float v) {
  dst[((size_t)(c >> 2) * HW + pix) * 4 + (c & 3)] = v;
}

// ---------------------------------------------------------------------------
// FRONT: builds QUAD-CHANNEL [c/4][HW][4] copies of all conv inputs:
//   x1q, x2q, x3q (composed 2x·2x from x), xq (copy of x), + wT transpose.
// ---------------------------------------------------------------------------
__global__ void k_front(const float* __restrict__ x, float* __restrict__ x1q,
                        float* __restrict__ x2q, float* __restrict__ x3q,
                        float* __restrict__ xq,
                        const float* __restrict__ d0, const float* __restrict__ d1,
                        const float* __restrict__ d2, const float* __restrict__ d3,
                        const float* __restrict__ c0, const float* __restrict__ c1,
                        const float* __restrict__ c2, const float* __restrict__ c3,
                        float* __restrict__ wT) {
  int idx = blockIdx.x * BDIM + threadIdx.x;
  if (idx < 65536) {
    int ox = idx & 31, oy = (idx >> 5) & 31, c = idx >> 10;
    pstore4(x1q, c, oy * 32 + ox, 1024,
            resize_one(x + c * 4096, 64, 64, oy, ox, 32, 32));
  } else if (idx < 1114112) {
    int j = idx - 65536;
    int ox = j & 127, oy = (j >> 7) & 127, c = j >> 14;
    pstore4(x2q, c, oy * 128 + ox, 16384,
            resize_one(x + c * 4096, 64, 64, oy, ox, 128, 128));
  } else if (idx < 5308416) {
    int j = idx - 1114112;
    int ox = j & 255, oy = (j >> 8) & 255, c = j >> 16;
    int ty[2], tx[2];
    float twy[2], twx[2];
    up2(oy, 128, ty, twy);
    up2(ox, 128, tx, twx);
    int ry[4], rx[4];
    float rwy[4], rwx[4];
#pragma unroll
    for (int a = 0; a < 2; ++a) {
      int t2[2];
      float w2[2];
      up2(ty[a], 64, t2, w2);
      ry[2 * a] = t2[0]; rwy[2 * a] = twy[a] * w2[0];
      ry[2 * a + 1] = t2[1]; rwy[2 * a + 1] = twy[a] * w2[1];
      up2(tx[a], 64, t2, w2);
      rx[2 * a] = t2[0]; rwx[2 * a] = twx[a] * w2[0];
      rx[2 * a + 1] = t2[1]; rwx[2 * a + 1] = twx[a] * w2[1];
    }
    const float* xc = x + c * 4096;
    float acc = 0.f;
#pragma unroll
    for (int a = 0; a < 4; ++a) {
      const float* row = xc + ry[a] * 64;
      float r = 0.f;
#pragma unroll
      for (int b = 0; b < 4; ++b) r += rwx[b] * row[rx[b]];
      acc += rwy[a] * r;
    }
    pstore4(x3q, c, oy * 256 + ox, 65536, acc);
  } else if (idx < 5386752) {
    int w = idx - 5308416;
    if (w < 36864) {
      int i = w / 9216, r = w % 9216;
      int o = r % 16, t = r / 16, c = t % 64, k = t / 64;
      const float* s = i == 0 ? d0 : i == 1 ? d1 : i == 2 ? d2 : d3;
      wT[w] = s[(o * 64 + c) * 9 + k];
    } else {
      int j = w - 36864;
      int i = j / 10368, r = j % 10368;
      int o = r % 18, t = r / 18, c = t % 64, k = t / 64;
      const float* s = i == 0 ? c0 : i == 1 ? c1 : i == 2 ? c2 : c3;
      wT[w] = s[(o * 64 + c) * 9 + k];
    }
  } else if (idx < 5648896) {
    int j = idx - 5386752;        // copy x -> quad xq
    int c = j >> 12, pix = j & 4095;
    pstore4(xq, c, pix, 4096, x[j]);
  }
}

// ---------------------------------------------------------------------------
// FUSED offset-conv + deformable conv + leaky, all 4 scales in one grid.
// QUAD-CHANNEL inputs: one dwordx4 load = 4 channels at a pixel (halves
// gather instruction count vs paired: TA transaction throughput is the wall).
// Segments big->small; per-segment bijective XCD swizzle (bl&7)*(n/8)+(bl>>3).
// Block = 512 thr = 8 waves; wave g owns quads {2g, 2g+1} (= channels
// 8g..8g+7). launch_bounds(512,4); VGPR must stay <=64 (occupancy cliff).
// ---------------------------------------------------------------------------
struct FArgs {
  const float* in[4];   // quad-channel images
  const float* wc[4];   // conv weights [k][c][o18]
  const float* bc[4];   // conv bias
  const float* wd[4];   // deform weights [k][c][o16] (crossed)
  const float* bd[4];   // deform bias (crossed)
  float* out[4];        // a1, a0, a2, a3 (scalar CHW)
};

__global__ __launch_bounds__(512, 4) void k_fused(FArgs A) {
  __shared__ float red[8 * 64 * 18];   // 36 KB, stride 18 (2-way = free)
  int b = blockIdx.x;
  int s, b0, nseg;
  if (b < 1024)      { s = 3; b0 = 0;    nseg = 1024; }
  else if (b < 1280) { s = 2; b0 = 1024; nseg = 256; }
  else if (b < 1344) { s = 1; b0 = 1280; nseg = 64; }
  else               { s = 0; b0 = 1344; nseg = 16; }
  int bl = b - b0;
  int swz = (bl & 7) * (nseg >> 3) + (bl >> 3);
  int H = 32 << s, W = H, lw = 5 + s, HW = H * W;
  int pad = 4 - s, dil = pad;
  int tid = threadIdx.x, lane = tid & 63;
  int gv = tid >> 6;
  int g = __builtin_amdgcn_readfirstlane(gv);
  int p = swz * 64 + lane;
  int py = p >> lw, px = p & (W - 1);
  const v4f* ipg4 = (const v4f*)A.in[s] + (size_t)(g * 2) * HW;  // quad 2g
  float* myred = &red[(size_t)(gv * 64 + lane) * 18];
  const float* lred = &red[lane * 18];

  // ---------------- phase A: offset conv (18 ch), partial over 8 channels
  {
    v2f accA[9];
#pragma unroll
    for (int j = 0; j < 9; ++j) accA[j] = (v2f){0.f, 0.f};
    const float* wT = A.wc[s];
#pragma unroll
    for (int ky = 0; ky < 3; ++ky) {
#pragma unroll
      for (int kx = 0; kx < 3; ++kx) {
        int k = ky * 3 + kx;
        int yy = py + ky - 1, xx = px + kx - 1;
        float msk = (yy >= 0 && yy < H && xx >= 0 && xx < W) ? 1.f : 0.f;
        int ai = min(max(yy, 0), H - 1) * W + min(max(xx, 0), W - 1);
        v4f va0 = ipg4[ai];                 // channels 8g..8g+3
        v4f va1 = ipg4[(size_t)HW + ai];    // channels 8g+4..8g+7
        const float* wkb = wT + (size_t)(k * 64 + g * 8) * 18;
#pragma unroll
        for (int e = 0; e < 4; ++e) {
          float v = va0[e] * msk;
          const v2f* w0 = (const v2f*)(wkb + e * 18);
          v2f vv = {v, v};
#pragma unroll
          for (int j = 0; j < 9; ++j) accA[j] = pkfma(w0[j], vv, accA[j]);
        }
#pragma unroll
        for (int e = 0; e < 4; ++e) {
          float v = va1[e] * msk;
          const v2f* w1 = (const v2f*)(wkb + (4 + e) * 18);
          v2f vv = {v, v};
#pragma unroll
          for (int j = 0; j < 9; ++j) accA[j] = pkfma(w1[j], vv, accA[j]);
        }
      }
    }
#pragma unroll
    for (int j = 0; j < 9; ++j) *(v2f*)(myred + 2 * j) = accA[j];
  }
  __syncthreads();
  v2f off2[9];
  {
    const v2f* bc2 = (const v2f*)A.bc[s];
#pragma unroll
    for (int j = 0; j < 9; ++j) {
      v2f v = bc2[j];
#pragma unroll
      for (int r = 0; r < 8; ++r) v += *(const v2f*)(lred + (size_t)r * 64 * 18 + 2 * j);
      off2[j] = v;
    }
  }
  __syncthreads();   // all reads of red done before phase-B overwrites

  // ---------------- phase B: deformable conv (16 ch) using off2
  v2f acc2[8];
#pragma unroll
  for (int j = 0; j < 8; ++j) acc2[j] = (v2f){0.f, 0.f};
  {
    const float* wT = A.wd[s];
#pragma unroll
    for (int ky = 0; ky < 3; ++ky) {
#pragma unroll
      for (int kx = 0; kx < 3; ++kx) {
        int k = ky * 3 + kx;
        float dy = off2[k].x;
        float dx = off2[k].y;
        float pyf = (float)(py - pad + ky * dil) + dy;
        float pxf = (float)(px - pad + kx * dil) + dx;
        float fy0 = floorf(pyf), fx0 = floorf(pxf);
        float wy = pyf - fy0, wxv = pxf - fx0;
        int y0 = (int)fy0, x0 = (int)fx0;
        float xg = (x0 >= -1 && x0 <= W - 1) ? 1.f : 0.f;
        float r0 = (1.f - wy) * ((y0 >= 0 && y0 < H) ? xg : 0.f);
        float r1 = wy * ((y0 + 1 >= 0 && y0 + 1 < H) ? xg : 0.f);
        float cl = 1.f - wxv, cr = wxv;
        bool xlo = x0 < 0, xhi = x0 > W - 2;
        float W00 = xlo ? r0 * cr : (xhi ? 0.f : r0 * cl);
        float W01 = xlo ? 0.f : (xhi ? r0 * cl : r0 * cr);
        float W10 = xlo ? r1 * cr : (xhi ? 0.f : r1 * cl);
        float W11 = xlo ? 0.f : (xhi ? r1 * cl : r1 * cr);
        int ax = min(max(x0, 0), W - 2);
        int cy0 = min(max(y0, 0), H - 1);
        int cy1 = min(max(y0 + 1, 0), H - 1);
        int A0 = cy0 * W + ax, A1 = cy1 * W + ax;
        v4f W00v = {W00, W00, W00, W00}, W01v = {W01, W01, W01, W01};
        v4f W10v = {W10, W10, W10, W10}, W11v = {W11, W11, W11, W11};
        const float* wkb = wT + (size_t)(k * 64 + g * 8) * 16;
        // quad 2g (channels 8g..8g+3): 4 loads, interp, outer product
        {
          v4f q00 = ipg4[A0], q01 = ipg4[A0 + 1];
          v4f q10 = ipg4[A1], q11 = ipg4[A1 + 1];
          v4f sv = q00 * W00v;
          sv = pkfma4(q01, W01v, sv);
          sv = pkfma4(q10, W10v, sv);
          sv = pkfma4(q11, W11v, sv);
#pragma unroll
          for (int e = 0; e < 4; ++e) {
            const v2f* w0 = (const v2f*)(wkb + e * 16);
            v2f vv = {sv[e], sv[e]};
#pragma unroll
            for (int j = 0; j < 8; ++j) acc2[j] = pkfma(w0[j], vv, acc2[j]);
          }
        }
        // quad 2g+1 (channels 8g+4..8g+7)
        {
          const v4f* ipq = ipg4 + (size_t)HW;
          v4f q00 = ipq[A0], q01 = ipq[A0 + 1];
          v4f q10 = ipq[A1], q11 = ipq[A1 + 1];
          v4f sv = q00 * W00v;
          sv = pkfma4(q01, W01v, sv);
          sv = pkfma4(q10, W10v, sv);
          sv = pkfma4(q11, W11v, sv);
#pragma unroll
          for (int e = 0; e < 4; ++e) {
            const v2f* w1 = (const v2f*)(wkb + (4 + e) * 16);
            v2f vv = {sv[e], sv[e]};
#pragma unroll
            for (int j = 0; j < 8; ++j) acc2[j] = pkfma(w1[j], vv, acc2[j]);
          }
        }
      }
    }
  }
  if (gv) {
    float* wr = &red[(size_t)((gv - 1) * 64 + lane) * 18];
#pragma unroll
    for (int j = 0; j < 8; ++j) *(v2f*)(wr + 2 * j) = acc2[j];
  }
  __syncthreads();
  if (!gv) {
    const v2f* bd2 = (const v2f*)A.bd[s];
    float* out = A.out[s];
#pragma unroll
    for (int j = 0; j < 8; ++j) {
      v2f v = acc2[j] + bd2[j];
#pragma unroll
      for (int r = 0; r < 7; ++r) v += *(const v2f*)(lred + (size_t)r * 64 * 18 + 2 * j);
      float vx = v.x, vy = v.y;
      vx = vx >= 0.f ? vx : 0.01f * vx;
      vy = vy >= 0.f ? vy : 0.01f * vy;
      out[(size_t)(2 * j) * HW + p] = vx;
      out[(size_t)(2 * j + 1) * HW + p] = vy;
    }
  }
}

// ---------------------------------------------------------------------------
// Horizontal downsample pass: a3 (16,256,256) -> t3 (16,256,64) 8 taps;
// a2 (16,128,128) -> t2 (16,128,64) 4 taps.
// ---------------------------------------------------------------------------
__global__ void k_hpass(const float* __restrict__ a2, const float* __restrict__ a3,
                        float* __restrict__ t2, float* __restrict__ t3) {
  int idx = blockIdx.x * BDIM + threadIdx.x;
  if (idx < 262144) {
    int ox = idx & 63, y = (idx >> 6) & 255, c = idx >> 14;
    float wx[8];
    int x0;
    int n = resize_taps(64, ox, 256, wx, &x0);
    const float* row = a3 + (size_t)c * 65536 + y * 256 + x0;
    float r = 0.f;
    for (int b = 0; b < n; ++b) r += wx[b] * row[b];
    t3[idx] = r;
  } else {
    int j = idx - 262144;
    if (j < 131072) {
      int ox = j & 63, y = (j >> 6) & 127, c = j >> 13;
      float wx[8];
      int x0;
      int n = resize_taps(64, ox, 128, wx, &x0);
      const float* row = a2 + (size_t)c * 16384 + y * 128 + x0;
      float r = 0.f;
      for (int b = 0; b < n; ++b) r += wx[b] * row[b];
      t2[j] = r;
    }
  }
}

__device__ __forceinline__ float gelu_f(float x) {
  return 0.5f * x * (1.f + erff(x * 0.70710678118654752f));
}

// Vertical taps + gelu combine.
__global__ void k_final2(const float* __restrict__ a0, const float* __restrict__ a1,
                         const float* __restrict__ t2, const float* __restrict__ t3,
                         float* __restrict__ out) {
  int i = blockIdx.x * BDIM + threadIdx.x;  // [0, 65536)
  int x = i & 63, y = (i >> 6) & 63, c = i >> 12;
  float x1r = resize_one(a1 + c * 1024, 32, 32, y, x, 64, 64);
  float wv[8];
  int y0;
  int n2 = resize_taps(64, y, 128, wv, &y0);
  const float* tp2 = t2 + (size_t)c * 8192 + y0 * 64 + x;
  float x2r = 0.f;
  for (int a = 0; a < n2; ++a) x2r += wv[a] * tp2[a * 64];
  int n3 = resize_taps(64, y, 256, wv, &y0);
  const float* tp3 = t3 + (size_t)c * 16384 + y0 * 64 + x;
  float x3r = 0.f;
  for (int a = 0; a < n3; ++a) x3r += wv[a] * tp3[a * 64];
  float av = a0[i];
  float l = gelu_f(x1r);
  float m = gelu_f(av - l);
  float h = gelu_f(x2r - av);
  float sv = gelu_f(x3r - x2r);
  out[i] = l;
  out[65536 + i] = m;
  out[131072 + i] = h;
  out[196608 + i] = sv;
}

static inline int cdiv(int a, int b) { return (a + b - 1) / b; }

extern "C" void kernel_launch(void* const* d_in, const int* in_sizes, int n_in,
                              void* d_out, int out_size, void* d_ws, size_t ws_size,
                              hipStream_t stream) {
  (void)in_sizes; (void)n_in; (void)out_size; (void)ws_size;
  const float* x = (const float*)d_in[0];
  const float* w_off[4] = {(const float*)d_in[1], (const float*)d_in[5],
                           (const float*)d_in[9], (const float*)d_in[13]};
  const float* b_off[4] = {(const float*)d_in[2], (const float*)d_in[6],
                           (const float*)d_in[10], (const float*)d_in[14]};
  const float* w_c[4] = {(const float*)d_in[3], (const float*)d_in[7],
                         (const float*)d_in[11], (const float*)d_in[15]};
  const float* b_c[4] = {(const float*)d_in[4], (const float*)d_in[8],
                         (const float*)d_in[12], (const float*)d_in[16]};
  float* out = (float*)d_out;

  // Workspace (floats), lifetime-aliased; peak 7,428,608 f = 29.7 MB.
  float* ws = (float*)d_ws;
  float* a0 = ws;                  // [0, 65536)
  float* a1 = ws + 65536;          // [65536, 81920)
  float* a2 = ws + 81920;          // [81920, 344064)
  float* wT = ws + 344064;         // [344064, 422400)
  float* x1q = ws + 422400;        // [422400, 487936)   dead after k_fused
  float* t3 = ws + 422400;         // ALIAS x1q+ (written post-fused)
  float* t2 = ws + 684544;         // [684544, 815616)
  float* x2q = ws + 875008;        // [875008, 1923584)
  float* x3q = ws + 1923584;       // [1923584, 6117888)
  float* a3 = ws + 6117888;        // [6117888, 7166464)
  float* xq = ws + 7166464;        // [7166464, 7428608)
  float* wTd = wT;                 // 4 x 9216
  float* wTc = wT + 36864;         // 4 x 10368

  FArgs fa;
  const float* ins[4] = {x1q, xq, x2q, x3q};
  float* as[4] = {a1, a0, a2, a3};
  for (int s = 0; s < 4; ++s) {
    fa.in[s] = ins[s];
    fa.wc[s] = wTc + s * 10368;
    fa.bc[s] = b_off[s];
    fa.wd[s] = wTd + (3 - s) * 9216;
    fa.bd[s] = b_c[3 - s];
    fa.out[s] = as[s];
  }

  k_front<<<cdiv(5648896, BDIM), BDIM, 0, stream>>>(
      x, x1q, x2q, x3q, xq, w_c[0], w_c[1], w_c[2], w_c[3],
      w_off[0], w_off[1], w_off[2], w_off[3], wT);
  k_fused<<<1360, 512, 0, stream>>>(fa);
  k_hpass<<<cdiv(262144 + 131072, BDIM), BDIM, 0, stream>>>(a2, a3, t2, t3);
  k_final2<<<cdiv(65536, BDIM), BDIM, 0, stream>>>(a0, a1, t2, t3, out);
}